// Round 4
// baseline (577.669 us; speedup 1.0000x reference)
//
#include <hip/hip_runtime.h>
#include <hip/hip_bf16.h>

// ============================================================================
// NexToU encoder block, MFMA bf16, [voxel][channel] layout. Round 4:
//  - MFMA operand swap: D rows = channel -> 8B C-stores (us4)
//  - mr_p2 writes xj only; conv g uses dual-stream loader (y1-affine | xj)
//  - MR mins on raw y1 (A>0), xj = A*(y1 - min3_raw)
//  - ewx2 reads bf16 xT (no f32 x re-read, no LDS)
//  - y3 split in 2 channel-halves, y4 in 2 voxel-halves (ws <= 302 MB)
// ============================================================================

typedef __hip_bfloat16 bf16;
typedef __attribute__((ext_vector_type(8))) short short8;
typedef __attribute__((ext_vector_type(4))) float f4;
typedef __attribute__((ext_vector_type(4))) unsigned short us4;

#define DEV static __device__ __forceinline__

constexpr int Sq  = 131072;   // D*H*W
constexpr int NVq = 262144;   // B*S

DEV float bu2f(unsigned short u) { return __uint_as_float(((unsigned)u) << 16); }
DEV unsigned short f2bu(float f) {
    unsigned i = __float_as_uint(f);
    unsigned r = i + 0x7FFFu + ((i >> 16) & 1u);   // RNE (finite inputs only)
    return (unsigned short)(r >> 16);
}
DEV void glds16(const void* g, void* l) {
    __builtin_amdgcn_global_load_lds(
        (const __attribute__((address_space(1))) unsigned*)g,
        (__attribute__((address_space(3))) unsigned*)l, 16, 0, 0);
}

// ---------------------------------------------------------------------------
// MFMA conv: Y[v][n] = sum_k A[v][k] * W[n][k] + bias[n], fused stats.
// BM=128 (4 waves x 32 rows), BN per dispatch, BK=64, KP = padded K.
// AMODE: 0 plain gload_lds from A0 (row stride CIRB)
//        1 dual-stream (A0 ch<192 | A1 ch>=192), per-c affine+lrelu (f2)
//        2 single stream, per-(b,c) affine+lrelu (fc2)
//        4 dual-stream concat: A0 = y1 per-c affine (no lrelu) | A1 = xj plain
// Store: operand-swapped MFMA -> rows = channel; lane stores 4 consecutive
// channels (8B us4). Yb used for blocks with b=1 (v >= 131072), row stride BN.
// ---------------------------------------------------------------------------
template<int CIRB, int KP, int BN, int AMODE, bool PERB>
__global__ __launch_bounds__(256)
void conv_k(const char* __restrict__ A0, const char* __restrict__ A1,
            const char* __restrict__ Wb, const float* __restrict__ bias,
            const float* __restrict__ cfA, const float* __restrict__ cfB,
            int n0g, bf16* __restrict__ Ya, bf16* __restrict__ Yb,
            float* __restrict__ part)
{
    constexpr int NSTEP = KP / 64;
    constexpr int NF = BN / 16;
    constexpr int BI = BN / 8;
    __shared__ __align__(16) char smem[16384 + BN * 128];
    char* As = smem;
    char* Bs = smem + 16384;

    const int tid = threadIdx.x;
    const int lane = tid & 63, wid = tid >> 6, l16 = lane & 15, lhi = lane >> 4;
    const int gm = blockIdx.x;
    const int v0 = gm * 128;
    const int b = gm >> 10;

    f4 acc[2][NF];
#pragma unroll
    for (int nf = 0; nf < NF; ++nf) {
        f4 bb = *(const f4*)(bias + n0g + nf * 16 + lhi * 4);
        acc[0][nf] = bb; acc[1][nf] = bb;
    }

    for (int s = 0; s < NSTEP; ++s) {
        // ---- stage B tile (weights)
        for (int i = wid; i < BI; i += 4) {
            int o = i * 8 + (lane >> 3);
            glds16(Wb + (size_t)(n0g + o) * (KP * 2) + s * 128 + (((lane & 7) ^ (o & 7)) << 4),
                   Bs + i * 1024);
        }
        // ---- stage A tile
        if constexpr (AMODE == 0) {
            for (int i = wid; i < 16; i += 4) {
                int r = i * 8 + (lane >> 3);
                glds16(A0 + (size_t)(v0 + r) * CIRB + s * 128 + (((lane & 7) ^ (r & 7)) << 4),
                       As + i * 1024);
            }
        } else {
#pragma unroll
            for (int j = 0; j < 4; ++j) {
                int idx = tid + 256 * j;           // v = idx>>3, u = idx&7
                int v = idx >> 3, u = idx & 7;
                int k8 = s * 8 + u;
                short8 hh;
                if constexpr (AMODE == 1) {        // f2: dual, affine+lrelu
                    const char* src = (k8 < 24)
                        ? (A0 + (size_t)(v0 + v) * 384 + k8 * 16)
                        : (A1 + (size_t)(v0 + v) * 384 + (k8 - 24) * 16);
                    short8 raw = *(const short8*)src;
                    int cb = k8 * 8;
                    f4 a0 = *(const f4*)(cfA + cb), a1 = *(const f4*)(cfA + cb + 4);
                    f4 d0 = *(const f4*)(cfB + cb), d1 = *(const f4*)(cfB + cb + 4);
#pragma unroll
                    for (int e = 0; e < 4; ++e) {
                        float t0 = fmaf(a0[e], bu2f((unsigned short)raw[e]),     d0[e]);
                        float t1 = fmaf(a1[e], bu2f((unsigned short)raw[e + 4]), d1[e]);
                        t0 = fmaxf(t0, 0.2f * t0);
                        t1 = fmaxf(t1, 0.2f * t1);
                        hh[e] = (short)f2bu(t0); hh[e + 4] = (short)f2bu(t1);
                    }
                } else if constexpr (AMODE == 2) { // fc2: per-(b,c) affine+lrelu
                    short8 raw = *(const short8*)(A0 + (size_t)(v0 + v) * 384 + k8 * 16);
                    int cb = b * KP + k8 * 8;
                    f4 a0 = *(const f4*)(cfA + cb), a1 = *(const f4*)(cfA + cb + 4);
                    f4 d0 = *(const f4*)(cfB + cb), d1 = *(const f4*)(cfB + cb + 4);
#pragma unroll
                    for (int e = 0; e < 4; ++e) {
                        float t0 = fmaf(a0[e], bu2f((unsigned short)raw[e]),     d0[e]);
                        float t1 = fmaf(a1[e], bu2f((unsigned short)raw[e + 4]), d1[e]);
                        t0 = fmaxf(t0, 0.2f * t0);
                        t1 = fmaxf(t1, 0.2f * t1);
                        hh[e] = (short)f2bu(t0); hh[e + 4] = (short)f2bu(t1);
                    }
                } else {                           // conv g: y1-affine | xj-plain
                    if (k8 < 12) {
                        short8 raw = *(const short8*)(A0 + (size_t)(v0 + v) * 192 + k8 * 16);
                        int cb = k8 * 8;
                        f4 a0 = *(const f4*)(cfA + cb), a1 = *(const f4*)(cfA + cb + 4);
                        f4 d0 = *(const f4*)(cfB + cb), d1 = *(const f4*)(cfB + cb + 4);
#pragma unroll
                        for (int e = 0; e < 4; ++e) {
                            hh[e]     = (short)f2bu(fmaf(a0[e], bu2f((unsigned short)raw[e]),     d0[e]));
                            hh[e + 4] = (short)f2bu(fmaf(a1[e], bu2f((unsigned short)raw[e + 4]), d1[e]));
                        }
                    } else {
                        hh = *(const short8*)(A1 + (size_t)(v0 + v) * 192 + (k8 - 12) * 16);
                    }
                }
                *(short8*)(As + v * 128 + ((u ^ (v & 7)) << 4)) = hh;
            }
        }
        __syncthreads();
        // ---- MFMA (operand-swapped: weights first -> D rows = channel)
#pragma unroll
        for (int ks = 0; ks < 2; ++ks) {
            int kg = ks * 4 + lhi;
            short8 av[2];
#pragma unroll
            for (int mf = 0; mf < 2; ++mf) {
                int v = wid * 32 + mf * 16 + l16;
                av[mf] = *(const short8*)(As + v * 128 + ((kg ^ (v & 7)) << 4));
            }
#pragma unroll
            for (int nf = 0; nf < NF; ++nf) {
                int o = nf * 16 + l16;
                short8 bv = *(const short8*)(Bs + o * 128 + ((kg ^ (o & 7)) << 4));
                acc[0][nf] = __builtin_amdgcn_mfma_f32_16x16x32_bf16(bv, av[0], acc[0][nf], 0, 0, 0);
                acc[1][nf] = __builtin_amdgcn_mfma_f32_16x16x32_bf16(bv, av[1], acc[1][nf], 0, 0, 0);
            }
        }
        __syncthreads();
    }

    // ---- store C: lane owns 4 consecutive channels (n = nf*16+lhi*4+r), col v=l16
    unsigned short* Yp = (unsigned short*)(b ? Yb : Ya);
    const int vloc = (gm & 1023) * 128 + wid * 32 + l16;
#pragma unroll
    for (int mf = 0; mf < 2; ++mf) {
        size_t rowo = (size_t)(vloc + mf * 16) * BN;
#pragma unroll
        for (int nf = 0; nf < NF; ++nf) {
            us4 p;
#pragma unroll
            for (int r = 0; r < 4; ++r) p[r] = f2bu(acc[mf][nf][r]);
            *(us4*)(Yp + rowo + nf * 16 + lhi * 4) = p;
        }
    }
    // ---- stats: per-channel sum/sumsq (reduce over v = l16 lanes)
    float* ps = (float*)smem;
#pragma unroll
    for (int nf = 0; nf < NF; ++nf) {
        f4 sv, qv;
#pragma unroll
        for (int r = 0; r < 4; ++r) {
            float a0 = acc[0][nf][r], a1 = acc[1][nf][r];
            float sm = a0 + a1;
            float sq = a0 * a0 + a1 * a1;
#pragma unroll
            for (int off = 1; off <= 8; off <<= 1) {
                sm += __shfl_xor(sm, off);
                sq += __shfl_xor(sq, off);
            }
            sv[r] = sm; qv[r] = sq;
        }
        if (l16 == 0) {
            *(f4*)&ps[(wid * 2 + 0) * BN + nf * 16 + lhi * 4] = sv;
            *(f4*)&ps[(wid * 2 + 1) * BN + nf * 16 + lhi * 4] = qv;
        }
    }
    __syncthreads();
    if (tid < BN) {
        float sm = ps[0 * BN + tid] + ps[2 * BN + tid] + ps[4 * BN + tid] + ps[6 * BN + tid];
        float sq = ps[1 * BN + tid] + ps[3 * BN + tid] + ps[5 * BN + tid] + ps[7 * BN + tid];
        int slot = PERB ? (b * 32 + (gm & 31)) : (gm & 63);
        float* pb = part + (size_t)slot * 2 * BN;
        atomicAdd(&pb[tid], sm);
        atomicAdd(&pb[BN + tid], sq);
    }
}

// ---------------------------------------------------------------------------
// partial sums -> affine coefs  A = g*rsqrt(var+eps), B = be - m*A
// part layout: [gy][64 slots][2][BN]
// ---------------------------------------------------------------------------
__global__ void finalize_k(const float* __restrict__ part, float* __restrict__ cf,
                           const float* __restrict__ g, const float* __restrict__ be,
                           int nStats, int CO, int BN, int perB, float invN)
{
    int s = blockIdx.x * 64 + threadIdx.x;
    if (s >= nStats) return;
    int ch = perB ? (s % CO) : s;
    int bb = perB ? (s / CO) : 0;
    int gy = ch / BN, c = ch - gy * BN;
    int j0 = perB ? bb * 32 : 0, cnt = perB ? 32 : 64;
    float sm = 0.f, sq = 0.f;
    for (int j = 0; j < cnt; ++j) {
        const float* pb = part + (size_t)(gy * 64 + j0 + j) * 2 * BN;
        sm += pb[c]; sq += pb[BN + c];
    }
    float m = sm * invN;
    float var = fmaf(-m, m, sq * invN);
    float A = g[ch] * rsqrtf(var + 1e-5f);
    cf[s] = A;
    cf[1024 + s] = fmaf(-m, A, be[ch]);
}

// ---------------------------------------------------------------------------
// weight prep: f32 [CO][CI] -> bf16 [CO][KP], K zero-padded
// ---------------------------------------------------------------------------
__global__ void wprep_k(const float* __restrict__ w0, const float* __restrict__ w1,
                        const float* __restrict__ w2, const float* __restrict__ w3,
                        const float* __restrict__ w4, bf16* __restrict__ Wb)
{
    int i = blockIdx.x * 256 + threadIdx.x;     // < 153600
    const float* src; int r, KP, CI, off;
    if (i < 12288)       { src = w0; r = i;          KP = 128; CI = 96;  off = 0; }
    else if (i < 49152)  { src = w1; r = i - 12288;  KP = 192; CI = 192; off = 12288; }
    else if (i < 67584)  { src = w2; r = i - 49152;  KP = 192; CI = 192; off = 49152; }
    else if (i < 116736) { src = w3; r = i - 67584;  KP = 128; CI = 96;  off = 67584; }
    else                 { src = w4; r = i - 116736; KP = 384; CI = 384; off = 116736; }
    int o = r / KP, k = r - o * KP;
    float v = (k < CI) ? src[o * CI + k] : 0.f;
    bf16 h; *(unsigned short*)&h = f2bu(v);
    Wb[off + r] = h;
}

// ---------------------------------------------------------------------------
// tin: x f32 [b][c][s] -> xT bf16 [v][96] via LDS transpose
// ---------------------------------------------------------------------------
__global__ __launch_bounds__(256)
void tin_k(const float* __restrict__ x, char* __restrict__ xT)
{
    __shared__ float ldsT[128 * 97];
    const int gm = blockIdx.x, b = gm >> 10, s0 = (gm & 1023) * 128;
    const int t = threadIdx.x;
#pragma unroll
    for (int i = 0; i < 12; ++i) {
        int idx = t + 256 * i;
        int c = idx >> 5, s4 = idx & 31;
        f4 r = *(const f4*)(x + ((size_t)(b * 96 + c) << 17) + s0 + s4 * 4);
#pragma unroll
        for (int j = 0; j < 4; ++j) ldsT[(s4 * 4 + j) * 97 + c] = r[j];
    }
    __syncthreads();
#pragma unroll
    for (int i = 0; i < 6; ++i) {
        int idx = t + 256 * i;
        int r = idx / 12, uc = idx % 12, cb = uc * 8;
        short8 o;
#pragma unroll
        for (int e = 0; e < 8; ++e) o[e] = (short)f2bu(ldsT[r * 97 + cb + e]);
        *(short8*)(xT + (size_t)(b * Sq + s0 + r) * 192 + uc * 16) = o;
    }
}

// ---------------------------------------------------------------------------
// MR pass 1a: dminp[b][h][w][dh][p][c] = raw min over d in half dh, parity p
// grid (wq4*dh2=8, h=64, b=2), 192 threads: (w = t/12, uc = t%12)
// ---------------------------------------------------------------------------
__global__ __launch_bounds__(192)
void mr_dmin_k(const char* __restrict__ y1, char* __restrict__ dminp)
{
    const int wq = blockIdx.x >> 1, dh = blockIdx.x & 1;
    const int h = blockIdx.y, b = blockIdx.z;
    const int t = threadIdx.x;
    const int w = wq * 16 + t / 12, uc = t % 12;
    const char* base = y1 + (size_t)(b * Sq + dh * 16 * 4096 + h * 64 + w) * 192 + uc * 16;
    float mn[2][8];
#pragma unroll
    for (int p = 0; p < 2; ++p)
#pragma unroll
        for (int e = 0; e < 8; ++e) mn[p][e] = 1e30f;
#pragma unroll 4
    for (int i = 0; i < 16; ++i) {
        short8 raw = *(const short8*)(base + (size_t)i * (4096 * 192));
        int p = i & 1;
#pragma unroll
        for (int e = 0; e < 8; ++e)
            mn[p][e] = fminf(mn[p][e], bu2f((unsigned short)raw[e]));
    }
#pragma unroll
    for (int p = 0; p < 2; ++p) {
        short8 o;
#pragma unroll
        for (int e = 0; e < 8; ++e) o[e] = (short)f2bu(mn[p][e]);
        *(short8*)(dminp + (size_t)((((b * 64 + h) * 64 + w) * 2 + dh) * 2 + p) * 192 + uc * 16) = o;
    }
}

// ---------------------------------------------------------------------------
// MR pass 1b: hminp[b][d][w][hq][p][c] = raw min over h in quarter hq, parity p
// grid (wq4*hq4=16, d=32, b=2), 192 threads
// ---------------------------------------------------------------------------
__global__ __launch_bounds__(192)
void mr_hmin_k(const char* __restrict__ y1, char* __restrict__ hminp)
{
    const int wq = blockIdx.x >> 2, hq = blockIdx.x & 3;
    const int d = blockIdx.y, b = blockIdx.z;
    const int t = threadIdx.x;
    const int w = wq * 16 + t / 12, uc = t % 12;
    const char* base = y1 + (size_t)(b * Sq + d * 4096 + hq * 16 * 64 + w) * 192 + uc * 16;
    float mn[2][8];
#pragma unroll
    for (int p = 0; p < 2; ++p)
#pragma unroll
        for (int e = 0; e < 8; ++e) mn[p][e] = 1e30f;
#pragma unroll 4
    for (int i = 0; i < 16; ++i) {
        short8 raw = *(const short8*)(base + (size_t)i * (64 * 192));
        int p = i & 1;
#pragma unroll
        for (int e = 0; e < 8; ++e)
            mn[p][e] = fminf(mn[p][e], bu2f((unsigned short)raw[e]));
    }
#pragma unroll
    for (int p = 0; p < 2; ++p) {
        short8 o;
#pragma unroll
        for (int e = 0; e < 8; ++e) o[e] = (short)f2bu(mn[p][e]);
        *(short8*)(hminp + (size_t)((((b * 32 + d) * 64 + w) * 4 + hq) * 2 + p) * 192 + uc * 16) = o;
    }
}

// ---------------------------------------------------------------------------
// MR pass 2: one block per row (b,d,h). Raw row -> LDS, raw w-min, then
// xj = A_c * (y1 - min(dminp x2, hminp x4, wmin)). grid (h=64, d=32, b=2).
// ---------------------------------------------------------------------------
__global__ __launch_bounds__(256)
void mr_p2_k(const char* __restrict__ y1, const float* __restrict__ cfA,
             const char* __restrict__ dminp, const char* __restrict__ hminp,
             char* __restrict__ xj)
{
    __shared__ __align__(16) char rowb[64 * 96 * 2];   // raw y1 row [w][c]
    __shared__ float wlds[2 * 96];                      // raw [wpar][c]
    const int h = blockIdx.x, d = blockIdx.y, b = blockIdx.z;
    const int t = threadIdx.x;

    short8 hv[3];
#pragma unroll
    for (int j = 0; j < 3; ++j) {
        int slot = t + 256 * j;
        int w = slot / 12, uc = slot % 12;
        short8 raw = *(const short8*)(y1 + (size_t)(b * Sq + d * 4096 + h * 64 + w) * 192 + uc * 16);
        hv[j] = raw;
        *(short8*)(rowb + slot * 16) = raw;
    }
    __syncthreads();
    if (t < 192) {
        int p = t / 96, c = t % 96;
        float m = 1e30f;
        for (int w2 = p; w2 < 64; w2 += 2)
            m = fminf(m, bu2f(*(const unsigned short*)(rowb + (w2 * 96 + c) * 2)));
        wlds[t] = m;
    }
    __syncthreads();
#pragma unroll
    for (int j = 0; j < 3; ++j) {
        int slot = t + 256 * j;
        int w = slot / 12, uc = slot % 12, cb = uc * 8;
        const char* dp = dminp + (size_t)((((b * 64 + h) * 64 + w) * 2) * 2 + (d & 1)) * 192 + uc * 16;
        short8 dm0 = *(const short8*)(dp);
        short8 dm1 = *(const short8*)(dp + 384);
        const char* hp = hminp + (size_t)((((b * 32 + d) * 64 + w) * 4) * 2 + (h & 1)) * 192 + uc * 16;
        short8 hm0 = *(const short8*)(hp);
        short8 hm1 = *(const short8*)(hp + 384);
        short8 hm2 = *(const short8*)(hp + 768);
        short8 hm3 = *(const short8*)(hp + 1152);
        f4 a0 = *(const f4*)(cfA + cb), a1 = *(const f4*)(cfA + cb + 4);
        short8 xo;
#pragma unroll
        for (int e = 0; e < 8; ++e) {
            float m = fminf(
                fminf(bu2f((unsigned short)dm0[e]), bu2f((unsigned short)dm1[e])),
                fminf(fminf(fminf(bu2f((unsigned short)hm0[e]), bu2f((unsigned short)hm1[e])),
                            fminf(bu2f((unsigned short)hm2[e]), bu2f((unsigned short)hm3[e]))),
                      wlds[(w & 1) * 96 + cb + e]));
            float A = (e < 4) ? a0[e] : a1[e - 4];
            xo[e] = (short)f2bu(A * (bu2f((unsigned short)hv[j][e]) - m));
        }
        *(short8*)(xj + (size_t)(b * Sq + d * 4096 + h * 64 + w) * 192 + uc * 16) = xo;
    }
}

// ---------------------------------------------------------------------------
// ewx2: x2[v][c] = A3*y2 + B3 + xT (all bf16 streams, no LDS)
// ---------------------------------------------------------------------------
__global__ __launch_bounds__(256)
void ewx2_k(const char* __restrict__ y2, const float* __restrict__ cfA,
            const float* __restrict__ cfB, const char* __restrict__ xT,
            char* __restrict__ x2)
{
    size_t ch0 = ((size_t)blockIdx.x * 256 + threadIdx.x) * 4;
#pragma unroll
    for (int j = 0; j < 4; ++j) {
        size_t chunk = ch0 + j;
        int uc = (int)(chunk % 12), cb = uc * 8;
        short8 yv = *(const short8*)(y2 + chunk * 16);
        short8 xv = *(const short8*)(xT + chunk * 16);
        f4 a0 = *(const f4*)(cfA + cb), a1 = *(const f4*)(cfA + cb + 4);
        f4 d0 = *(const f4*)(cfB + cb), d1 = *(const f4*)(cfB + cb + 4);
        short8 o;
#pragma unroll
        for (int e = 0; e < 4; ++e) {
            float t0 = fmaf(a0[e], bu2f((unsigned short)yv[e]),     d0[e]) + bu2f((unsigned short)xv[e]);
            float t1 = fmaf(a1[e], bu2f((unsigned short)yv[e + 4]), d1[e]) + bu2f((unsigned short)xv[e + 4]);
            o[e]     = (short)f2bu(t0);
            o[e + 4] = (short)f2bu(t1);
        }
        *(short8*)(x2 + chunk * 16) = o;
    }
}

// ---------------------------------------------------------------------------
// tout: out f32 [b][c][s] = A5*y4 + B5 + x2   (transpose via LDS)
// y4 split by voxel-half (y4a: b=0, y4b: b=1), local row stride 192B
// ---------------------------------------------------------------------------
__global__ __launch_bounds__(256)
void tout_k(const char* __restrict__ y4a, const char* __restrict__ y4b,
            const float* __restrict__ cfA, const float* __restrict__ cfB,
            const char* __restrict__ x2, float* __restrict__ outp)
{
    __shared__ float ldsT[128 * 97];
    const int gm = blockIdx.x, b = gm >> 10, s0 = (gm & 1023) * 128;
    const int t = threadIdx.x;
    const char* y4 = b ? y4b : y4a;
#pragma unroll
    for (int i = 0; i < 6; ++i) {
        int idx = t + 256 * i;
        int r = idx / 12, uc = idx % 12, cb = uc * 8;
        short8 yv = *(const short8*)(y4 + (size_t)(s0 + r) * 192 + uc * 16);
        short8 xv = *(const short8*)(x2 + (size_t)(b * Sq + s0 + r) * 192 + uc * 16);
        f4 a0 = *(const f4*)(cfA + cb), a1 = *(const f4*)(cfA + cb + 4);
        f4 d0 = *(const f4*)(cfB + cb), d1 = *(const f4*)(cfB + cb + 4);
#pragma unroll
        for (int e = 0; e < 4; ++e) {
            ldsT[r * 97 + cb + e]     = fmaf(a0[e], bu2f((unsigned short)yv[e]),     d0[e]) + bu2f((unsigned short)xv[e]);
            ldsT[r * 97 + cb + e + 4] = fmaf(a1[e], bu2f((unsigned short)yv[e + 4]), d1[e]) + bu2f((unsigned short)xv[e + 4]);
        }
    }
    __syncthreads();
#pragma unroll
    for (int i = 0; i < 12; ++i) {
        int idx = t + 256 * i;
        int c = idx >> 5, s4 = idx & 31;
        f4 o;
#pragma unroll
        for (int j = 0; j < 4; ++j) o[j] = ldsT[(s4 * 4 + j) * 97 + c];
        *(f4*)(outp + ((size_t)(b * 96 + c) << 17) + s0 + s4 * 4) = o;
    }
}

// ===========================================================================
extern "C" void kernel_launch(void* const* d_in, const int* in_sizes, int n_in,
                              void* d_out, int out_size, void* d_ws, size_t ws_size,
                              hipStream_t stream)
{
    (void)in_sizes; (void)n_in; (void)out_size; (void)ws_size;

    const float* x      = (const float*)d_in[0];
    const float* w_fc1  = (const float*)d_in[1];
    const float* b_fc1  = (const float*)d_in[2];
    const float* g_bn1  = (const float*)d_in[3];
    const float* be_bn1 = (const float*)d_in[4];
    const float* w_g    = (const float*)d_in[5];
    const float* b_g    = (const float*)d_in[6];
    const float* g_in   = (const float*)d_in[7];
    const float* be_in  = (const float*)d_in[8];
    const float* w_fc2  = (const float*)d_in[9];
    const float* b_fc2  = (const float*)d_in[10];
    const float* g_bn2  = (const float*)d_in[11];
    const float* be_bn2 = (const float*)d_in[12];
    const float* w_f1   = (const float*)d_in[13];
    const float* b_f1   = (const float*)d_in[14];
    const float* g_bnf1 = (const float*)d_in[15];
    const float* be_bnf1= (const float*)d_in[16];
    const float* w_f2   = (const float*)d_in[17];
    const float* b_f2   = (const float*)d_in[18];
    const float* g_bnf2 = (const float*)d_in[19];
    const float* be_bnf2= (const float*)d_in[20];
    float* outp = (float*)d_out;

    char* W = (char*)d_ws;
    // layout (bytes):
    char* xT    = W;                      // [0, 50331648)        tin -> ewx2
    char* y1    = W + 50331648;           // [50.3M, 100.7M)      fc1 -> conv g
    char* dminp = W + 100663296;          // [100.7M, 113.2M)     mr1 -> mr_p2
    char* hminp = W + 113246208;          // [113.2M, 125.8M)     mr1 -> mr_p2
    char* xj    = W + 125829120;          // [125.8M, 176.2M)     mr_p2 -> conv g
    char* yg    = W + 176160768;          // [176.2M, 276.8M)     conv g -> fc2
    char* y2    = W + 50331648;           // reuse y1 slot        fc2 -> ewx2
    char* x2    = W + 125829120;          // reuse xj slot        ewx2 -> tout
    char* y3A   = W;                      // [0, 100.7M)          f1 -> f2 (ch 0-191)
    char* y3B   = W + 176160768;          // [176.2M, 276.8M)     f1 -> f2 (ch 192-383)
    char* y4a   = W + 100663296;          // [100.7M, 125.8M)     f2 -> tout (b=0)
    char* y4b   = W + 276824064;          // [276.8M, 302.0M)     f2 -> tout (b=1)
    char* M     = W + 301989888;
    bf16*  Wb   = (bf16*)M;               // 307200 B
    float* cf   = (float*)(M + 307200);   // 5 slots x 2048 f32
    float* part = (float*)(M + 348160);   // 5 slots x 49152 f32

    hipMemsetAsync(part, 0, 5 * 196608, stream);

    const float invBN = 1.f / (float)NVq, invIN = 1.f / (float)Sq;
    dim3 blk(256);
    float* c1 = cf, *c2 = cf + 2048, *c3 = cf + 4096, *c4 = cf + 6144, *c5 = cf + 8192;

    wprep_k<<<600, blk, 0, stream>>>(w_fc1, w_g, w_fc2, w_f1, w_f2, Wb);
    tin_k<<<2048, blk, 0, stream>>>(x, xT);

    // fc1: 96 -> 96 (plain, gload_lds)
    conv_k<192, 128, 96, 0, false><<<2048, blk, 0, stream>>>(
        xT, nullptr, (const char*)Wb, b_fc1, nullptr, nullptr, 0,
        (bf16*)y1, (bf16*)y1 + (size_t)131072 * 96, part);
    finalize_k<<<2, 64, 0, stream>>>(part, c1, g_bn1, be_bn1, 96, 96, 96, 0, invBN);

    // MRConv on raw y1 (A>0): partial mins, then xj = A*(y1 - min3)
    mr_dmin_k<<<dim3(8, 64, 2), dim3(192), 0, stream>>>(y1, dminp);
    mr_hmin_k<<<dim3(16, 32, 2), dim3(192), 0, stream>>>(y1, hminp);
    mr_p2_k<<<dim3(64, 32, 2), blk, 0, stream>>>(y1, c1, dminp, hminp, xj);

    // grapher conv: concat(y1-affine, xj) 192 -> 192, IN stats per (b,c)
    conv_k<192, 192, 192, 4, true><<<2048, blk, 0, stream>>>(
        y1, xj, (const char*)Wb + 24576, b_g, c1, c1 + 1024, 0,
        (bf16*)yg, (bf16*)yg + (size_t)131072 * 192, part + 49152);
    finalize_k<<<6, 64, 0, stream>>>(part + 49152, c2, g_in, be_in, 384, 192, 192, 1, invIN);

    // fc2: 192 -> 96, loader = lrelu(A2*yg+B2) per (b,c)
    conv_k<384, 192, 96, 2, false><<<2048, blk, 0, stream>>>(
        yg, nullptr, (const char*)Wb + 98304, b_fc2, c2, c2 + 1024, 0,
        (bf16*)y2, (bf16*)y2 + (size_t)131072 * 96, part + 98304);
    finalize_k<<<2, 64, 0, stream>>>(part + 98304, c3, g_bn2, be_bn2, 96, 96, 96, 0, invBN);

    // x2 = A3*y2 + B3 + xT
    ewx2_k<<<3072, blk, 0, stream>>>(y2, c3, c3 + 1024, xT, x2);

    // f1: 96 -> 384, two channel-half dispatches
    conv_k<192, 128, 192, 0, false><<<2048, blk, 0, stream>>>(
        x2, nullptr, (const char*)Wb + 135168, b_f1, nullptr, nullptr, 0,
        (bf16*)y3A, (bf16*)y3A + (size_t)131072 * 192, part + 147456);
    conv_k<192, 128, 192, 0, false><<<2048, blk, 0, stream>>>(
        x2, nullptr, (const char*)Wb + 135168, b_f1, nullptr, nullptr, 192,
        (bf16*)y3B, (bf16*)y3B + (size_t)131072 * 192, part + 147456 + 24576);
    finalize_k<<<6, 64, 0, stream>>>(part + 147456, c4, g_bnf1, be_bnf1, 384, 384, 192, 0, invBN);

    // f2: 384 -> 96, dual-stream loader = lrelu(A4*y3+B4); y4 split by voxel-half
    conv_k<384, 384, 96, 1, false><<<2048, blk, 0, stream>>>(
        y3A, y3B, (const char*)Wb + 233472, b_f2, c4, c4 + 1024, 0,
        (bf16*)y4a, (bf16*)y4b, part + 196608);
    finalize_k<<<2, 64, 0, stream>>>(part + 196608, c5, g_bnf2, be_bnf2, 96, 96, 96, 0, invBN);

    tout_k<<<2048, blk, 0, stream>>>(y4a, y4b, c5, c5 + 1024, x2, outp);
}

// Round 5
// 511.365 us; speedup vs baseline: 1.1297x; 1.1297x over previous
//
#include <hip/hip_runtime.h>
#include <hip/hip_bf16.h>

// ============================================================================
// NexToU encoder block, MFMA bf16, [voxel][channel] layout. Round 5:
// round-3 conv_k (proven 3.3 TB/s) + round-4 traffic cuts:
//  - mr writes xj only (A-premultiplied); conv g dual-stream (y1-affine | xj)
//  - MR mins on raw y1 (A>0, B cancels): xj = A*(y1 - min3_raw)
//  - ewx2 reads bf16 xT (no f32 re-read, no LDS)
//  - f1 single dispatch grid (2048,2) -> full y3 [v][384] (LLC reuse of x2)
// ============================================================================

typedef __hip_bfloat16 bf16;
typedef __attribute__((ext_vector_type(8))) short short8;
typedef __attribute__((ext_vector_type(4))) float f4;

#define DEV static __device__ __forceinline__

constexpr int Sq  = 131072;   // D*H*W
constexpr int NVq = 262144;   // B*S

DEV float bu2f(unsigned short u) { return __uint_as_float(((unsigned)u) << 16); }
DEV unsigned short f2bu(float f) {
    unsigned i = __float_as_uint(f);
    unsigned r = i + 0x7FFFu + ((i >> 16) & 1u);   // RNE (finite inputs only)
    return (unsigned short)(r >> 16);
}
DEV void glds16(const void* g, void* l) {
    __builtin_amdgcn_global_load_lds(
        (const __attribute__((address_space(1))) unsigned*)g,
        (__attribute__((address_space(3))) unsigned*)l, 16, 0, 0);
}

// ---------------------------------------------------------------------------
// MFMA conv: Y[v][n] = sum_k A[v][k] * W[n][k] + bias[n], fused stats.
// BM=128 (4 waves x 32 rows), BN per gy, BK=64, KP = padded K, CO = row stride.
// AMODE: 0 plain gload_lds from A0 (row stride CIRB bytes)
//        1 single stream, per-c affine+lrelu (f2; CIRB=768)
//        2 single stream, per-(b,c) affine+lrelu (fc2; CIRB=384)
//        4 dual-stream concat: A0 = y1 per-c affine (no lrelu) | A1 = xj plain
// LDS: chunk u of row v stored at unit u^(v&7) -> conflict-free ds_read_b128.
// ---------------------------------------------------------------------------
template<int CIRB, int KP, int CO, int BN, int AMODE, bool PERB>
__global__ __launch_bounds__(256)
void conv_k(const char* __restrict__ A0, const char* __restrict__ A1,
            const char* __restrict__ Wb, const float* __restrict__ bias,
            const float* __restrict__ cfA, const float* __restrict__ cfB,
            bf16* __restrict__ Y, float* __restrict__ part)
{
    constexpr int NSTEP = KP / 64;
    constexpr int NF = BN / 16;
    constexpr int BI = BN / 8;
    __shared__ __align__(16) char smem[16384 + BN * 128];
    char* As = smem;
    char* Bs = smem + 16384;

    const int tid = threadIdx.x;
    const int lane = tid & 63, wid = tid >> 6, l16 = lane & 15, lhi = lane >> 4;
    const int gm = blockIdx.x, gy = blockIdx.y;
    const int v0 = gm * 128;
    const int b = gm >> 10;          // 1024 M-blocks per batch sample
    const int n0g = gy * BN;

    f4 acc[2][NF];
#pragma unroll
    for (int nf = 0; nf < NF; ++nf) {
        float bb = bias[n0g + nf * 16 + l16];
        f4 t = {bb, bb, bb, bb};
        acc[0][nf] = t; acc[1][nf] = t;
    }

    for (int s = 0; s < NSTEP; ++s) {
        // ---- stage B tile (weights)
        for (int i = wid; i < BI; i += 4) {
            int o = i * 8 + (lane >> 3);
            glds16(Wb + (size_t)(n0g + o) * (KP * 2) + s * 128 + (((lane & 7) ^ (o & 7)) << 4),
                   Bs + i * 1024);
        }
        // ---- stage A tile
        if constexpr (AMODE == 0) {
            for (int i = wid; i < 16; i += 4) {
                int r = i * 8 + (lane >> 3);
                glds16(A0 + (size_t)(v0 + r) * CIRB + s * 128 + (((lane & 7) ^ (r & 7)) << 4),
                       As + i * 1024);
            }
        } else {
#pragma unroll
            for (int j = 0; j < 4; ++j) {
                int idx = tid + 256 * j;           // v = idx>>3, u = idx&7
                int v = idx >> 3, u = idx & 7;
                int k8 = s * 8 + u;
                short8 hh;
                if constexpr (AMODE == 1) {        // f2: per-c affine+lrelu
                    short8 raw = *(const short8*)(A0 + (size_t)(v0 + v) * CIRB + k8 * 16);
                    int cb = k8 * 8;
                    f4 a0 = *(const f4*)(cfA + cb), a1 = *(const f4*)(cfA + cb + 4);
                    f4 d0 = *(const f4*)(cfB + cb), d1 = *(const f4*)(cfB + cb + 4);
#pragma unroll
                    for (int e = 0; e < 4; ++e) {
                        float t0 = fmaf(a0[e], bu2f((unsigned short)raw[e]),     d0[e]);
                        float t1 = fmaf(a1[e], bu2f((unsigned short)raw[e + 4]), d1[e]);
                        t0 = fmaxf(t0, 0.2f * t0);
                        t1 = fmaxf(t1, 0.2f * t1);
                        hh[e] = (short)f2bu(t0); hh[e + 4] = (short)f2bu(t1);
                    }
                } else if constexpr (AMODE == 2) { // fc2: per-(b,c) affine+lrelu
                    short8 raw = *(const short8*)(A0 + (size_t)(v0 + v) * CIRB + k8 * 16);
                    int cb = b * KP + k8 * 8;
                    f4 a0 = *(const f4*)(cfA + cb), a1 = *(const f4*)(cfA + cb + 4);
                    f4 d0 = *(const f4*)(cfB + cb), d1 = *(const f4*)(cfB + cb + 4);
#pragma unroll
                    for (int e = 0; e < 4; ++e) {
                        float t0 = fmaf(a0[e], bu2f((unsigned short)raw[e]),     d0[e]);
                        float t1 = fmaf(a1[e], bu2f((unsigned short)raw[e + 4]), d1[e]);
                        t0 = fmaxf(t0, 0.2f * t0);
                        t1 = fmaxf(t1, 0.2f * t1);
                        hh[e] = (short)f2bu(t0); hh[e + 4] = (short)f2bu(t1);
                    }
                } else {                           // conv g: y1-affine | xj-plain
                    if (k8 < 12) {
                        short8 raw = *(const short8*)(A0 + (size_t)(v0 + v) * 192 + k8 * 16);
                        int cb = k8 * 8;
                        f4 a0 = *(const f4*)(cfA + cb), a1 = *(const f4*)(cfA + cb + 4);
                        f4 d0 = *(const f4*)(cfB + cb), d1 = *(const f4*)(cfB + cb + 4);
#pragma unroll
                        for (int e = 0; e < 4; ++e) {
                            hh[e]     = (short)f2bu(fmaf(a0[e], bu2f((unsigned short)raw[e]),     d0[e]));
                            hh[e + 4] = (short)f2bu(fmaf(a1[e], bu2f((unsigned short)raw[e + 4]), d1[e]));
                        }
                    } else {
                        hh = *(const short8*)(A1 + (size_t)(v0 + v) * 192 + (k8 - 12) * 16);
                    }
                }
                *(short8*)(As + v * 128 + ((u ^ (v & 7)) << 4)) = hh;
            }
        }
        __syncthreads();
        // ---- MFMA
#pragma unroll
        for (int ks = 0; ks < 2; ++ks) {
            int kg = ks * 4 + lhi;
            short8 av[2];
#pragma unroll
            for (int mf = 0; mf < 2; ++mf) {
                int v = wid * 32 + mf * 16 + l16;
                av[mf] = *(const short8*)(As + v * 128 + ((kg ^ (v & 7)) << 4));
            }
#pragma unroll
            for (int nf = 0; nf < NF; ++nf) {
                int o = nf * 16 + l16;
                short8 bv = *(const short8*)(Bs + o * 128 + ((kg ^ (o & 7)) << 4));
                acc[0][nf] = __builtin_amdgcn_mfma_f32_16x16x32_bf16(av[0], bv, acc[0][nf], 0, 0, 0);
                acc[1][nf] = __builtin_amdgcn_mfma_f32_16x16x32_bf16(av[1], bv, acc[1][nf], 0, 0, 0);
            }
        }
        __syncthreads();
    }

    // ---- store C (D frag: col = lane&15 -> n, row = (lane>>4)*4 + reg -> v)
#pragma unroll
    for (int mf = 0; mf < 2; ++mf) {
        int vb = v0 + wid * 32 + mf * 16 + lhi * 4;
#pragma unroll
        for (int nf = 0; nf < NF; ++nf) {
            int n = n0g + nf * 16 + l16;
#pragma unroll
            for (int r = 0; r < 4; ++r) {
                bf16 o; *(unsigned short*)&o = f2bu(acc[mf][nf][r]);
                Y[(size_t)(vb + r) * CO + n] = o;
            }
        }
    }
    // ---- stats: per-channel sum / sumsq
    float* ps = (float*)smem;      // [4 waves][2][BN]
#pragma unroll
    for (int nf = 0; nf < NF; ++nf) {
        float sm = 0.f, sq = 0.f;
#pragma unroll
        for (int mf = 0; mf < 2; ++mf)
#pragma unroll
            for (int r = 0; r < 4; ++r) {
                float v = acc[mf][nf][r];
                sm += v; sq += v * v;
            }
        sm += __shfl_xor(sm, 16); sq += __shfl_xor(sq, 16);
        sm += __shfl_xor(sm, 32); sq += __shfl_xor(sq, 32);
        if (lane < 16) {
            ps[(wid * 2 + 0) * BN + nf * 16 + lane] = sm;
            ps[(wid * 2 + 1) * BN + nf * 16 + lane] = sq;
        }
    }
    __syncthreads();
    if (tid < BN) {
        float sm = ps[0 * BN + tid] + ps[2 * BN + tid] + ps[4 * BN + tid] + ps[6 * BN + tid];
        float sq = ps[1 * BN + tid] + ps[3 * BN + tid] + ps[5 * BN + tid] + ps[7 * BN + tid];
        int slot = PERB ? (b * 32 + (gm & 31)) : (gm & 63);
        float* pb = part + (size_t)(gy * 64 + slot) * 2 * BN;
        atomicAdd(&pb[tid], sm);
        atomicAdd(&pb[BN + tid], sq);
    }
}

// ---------------------------------------------------------------------------
// partial sums -> affine coefs  A = g*rsqrt(var+eps), B = be - m*A
// part layout: [gy][64 slots][2][BN]
// ---------------------------------------------------------------------------
__global__ void finalize_k(const float* __restrict__ part, float* __restrict__ cf,
                           const float* __restrict__ g, const float* __restrict__ be,
                           int nStats, int CO, int BN, int perB, float invN)
{
    int s = blockIdx.x * 64 + threadIdx.x;
    if (s >= nStats) return;
    int ch = perB ? (s % CO) : s;
    int bb = perB ? (s / CO) : 0;
    int gy = ch / BN, c = ch - gy * BN;
    int j0 = perB ? bb * 32 : 0, cnt = perB ? 32 : 64;
    float sm = 0.f, sq = 0.f;
    for (int j = 0; j < cnt; ++j) {
        const float* pb = part + (size_t)(gy * 64 + j0 + j) * 2 * BN;
        sm += pb[c]; sq += pb[BN + c];
    }
    float m = sm * invN;
    float var = fmaf(-m, m, sq * invN);
    float A = g[ch] * rsqrtf(var + 1e-5f);
    cf[s] = A;
    cf[1024 + s] = fmaf(-m, A, be[ch]);
}

// ---------------------------------------------------------------------------
// weight prep: f32 [CO][CI] -> bf16 [CO][KP], K zero-padded
// ---------------------------------------------------------------------------
__global__ void wprep_k(const float* __restrict__ w0, const float* __restrict__ w1,
                        const float* __restrict__ w2, const float* __restrict__ w3,
                        const float* __restrict__ w4, bf16* __restrict__ Wb)
{
    int i = blockIdx.x * 256 + threadIdx.x;     // < 153600
    const float* src; int r, KP, CI, off;
    if (i < 12288)       { src = w0; r = i;          KP = 128; CI = 96;  off = 0; }
    else if (i < 49152)  { src = w1; r = i - 12288;  KP = 192; CI = 192; off = 12288; }
    else if (i < 67584)  { src = w2; r = i - 49152;  KP = 192; CI = 192; off = 49152; }
    else if (i < 116736) { src = w3; r = i - 67584;  KP = 128; CI = 96;  off = 67584; }
    else                 { src = w4; r = i - 116736; KP = 384; CI = 384; off = 116736; }
    int o = r / KP, k = r - o * KP;
    float v = (k < CI) ? src[o * CI + k] : 0.f;
    bf16 h; *(unsigned short*)&h = f2bu(v);
    Wb[off + r] = h;
}

// ---------------------------------------------------------------------------
// tin: x f32 [b][c][s] -> xT bf16 [v][96] via LDS transpose
// ---------------------------------------------------------------------------
__global__ __launch_bounds__(256)
void tin_k(const float* __restrict__ x, char* __restrict__ xT)
{
    __shared__ float ldsT[128 * 97];
    const int gm = blockIdx.x, b = gm >> 10, s0 = (gm & 1023) * 128;
    const int t = threadIdx.x;
#pragma unroll
    for (int i = 0; i < 12; ++i) {
        int idx = t + 256 * i;
        int c = idx >> 5, s4 = idx & 31;
        f4 r = *(const f4*)(x + ((size_t)(b * 96 + c) << 17) + s0 + s4 * 4);
#pragma unroll
        for (int j = 0; j < 4; ++j) ldsT[(s4 * 4 + j) * 97 + c] = r[j];
    }
    __syncthreads();
#pragma unroll
    for (int i = 0; i < 6; ++i) {
        int idx = t + 256 * i;
        int r = idx / 12, uc = idx % 12, cb = uc * 8;
        short8 o;
#pragma unroll
        for (int e = 0; e < 8; ++e) o[e] = (short)f2bu(ldsT[r * 97 + cb + e]);
        *(short8*)(xT + (size_t)(b * Sq + s0 + r) * 192 + uc * 16) = o;
    }
}

// ---------------------------------------------------------------------------
// MR pass 1a: dminp[b][h][w][dh][p][c] = raw min over d in half dh, parity p
// grid (wq4*dh2=8, h=64, b=2), 192 threads: (w = t/12, uc = t%12)
// ---------------------------------------------------------------------------
__global__ __launch_bounds__(192)
void mr_dmin_k(const char* __restrict__ y1, char* __restrict__ dminp)
{
    const int wq = blockIdx.x >> 1, dh = blockIdx.x & 1;
    const int h = blockIdx.y, b = blockIdx.z;
    const int t = threadIdx.x;
    const int w = wq * 16 + t / 12, uc = t % 12;
    const char* base = y1 + (size_t)(b * Sq + dh * 16 * 4096 + h * 64 + w) * 192 + uc * 16;
    float mn[2][8];
#pragma unroll
    for (int p = 0; p < 2; ++p)
#pragma unroll
        for (int e = 0; e < 8; ++e) mn[p][e] = 1e30f;
#pragma unroll 4
    for (int i = 0; i < 16; ++i) {
        short8 raw = *(const short8*)(base + (size_t)i * (4096 * 192));
        int p = i & 1;
#pragma unroll
        for (int e = 0; e < 8; ++e)
            mn[p][e] = fminf(mn[p][e], bu2f((unsigned short)raw[e]));
    }
#pragma unroll
    for (int p = 0; p < 2; ++p) {
        short8 o;
#pragma unroll
        for (int e = 0; e < 8; ++e) o[e] = (short)f2bu(mn[p][e]);
        *(short8*)(dminp + (size_t)((((b * 64 + h) * 64 + w) * 2 + dh) * 2 + p) * 192 + uc * 16) = o;
    }
}

// ---------------------------------------------------------------------------
// MR pass 1b: hminp[b][d][w][hq][p][c] = raw min over h in quarter hq, parity p
// grid (wq4*hq4=16, d=32, b=2), 192 threads
// ---------------------------------------------------------------------------
__global__ __launch_bounds__(192)
void mr_hmin_k(const char* __restrict__ y1, char* __restrict__ hminp)
{
    const int wq = blockIdx.x >> 2, hq = blockIdx.x & 3;
    const int d = blockIdx.y, b = blockIdx.z;
    const int t = threadIdx.x;
    const int w = wq * 16 + t / 12, uc = t % 12;
    const char* base = y1 + (size_t)(b * Sq + d * 4096 + hq * 16 * 64 + w) * 192 + uc * 16;
    float mn[2][8];
#pragma unroll
    for (int p = 0; p < 2; ++p)
#pragma unroll
        for (int e = 0; e < 8; ++e) mn[p][e] = 1e30f;
#pragma unroll 4
    for (int i = 0; i < 16; ++i) {
        short8 raw = *(const short8*)(base + (size_t)i * (64 * 192));
        int p = i & 1;
#pragma unroll
        for (int e = 0; e < 8; ++e)
            mn[p][e] = fminf(mn[p][e], bu2f((unsigned short)raw[e]));
    }
#pragma unroll
    for (int p = 0; p < 2; ++p) {
        short8 o;
#pragma unroll
        for (int e = 0; e < 8; ++e) o[e] = (short)f2bu(mn[p][e]);
        *(short8*)(hminp + (size_t)((((b * 32 + d) * 64 + w) * 4 + hq) * 2 + p) * 192 + uc * 16) = o;
    }
}

// ---------------------------------------------------------------------------
// MR pass 2: one block per row (b,d,h). Raw row -> LDS, raw w-min, then
// xj = A_c * (y1 - min(dminp x2, hminp x4, wmin)). grid (h=64, d=32, b=2).
// ---------------------------------------------------------------------------
__global__ __launch_bounds__(256)
void mr_p2_k(const char* __restrict__ y1, const float* __restrict__ cfA,
             const char* __restrict__ dminp, const char* __restrict__ hminp,
             char* __restrict__ xj)
{
    __shared__ __align__(16) char rowb[64 * 96 * 2];   // raw y1 row [w][c]
    __shared__ float wlds[2 * 96];                      // raw [wpar][c]
    const int h = blockIdx.x, d = blockIdx.y, b = blockIdx.z;
    const int t = threadIdx.x;

    short8 hv[3];
#pragma unroll
    for (int j = 0; j < 3; ++j) {
        int slot = t + 256 * j;
        int w = slot / 12, uc = slot % 12;
        short8 raw = *(const short8*)(y1 + (size_t)(b * Sq + d * 4096 + h * 64 + w) * 192 + uc * 16);
        hv[j] = raw;
        *(short8*)(rowb + slot * 16) = raw;
    }
    __syncthreads();
    if (t < 192) {
        int p = t / 96, c = t % 96;
        float m = 1e30f;
        for (int w2 = p; w2 < 64; w2 += 2)
            m = fminf(m, bu2f(*(const unsigned short*)(rowb + (w2 * 96 + c) * 2)));
        wlds[t] = m;
    }
    __syncthreads();
#pragma unroll
    for (int j = 0; j < 3; ++j) {
        int slot = t + 256 * j;
        int w = slot / 12, uc = slot % 12, cb = uc * 8;
        const char* dp = dminp + (size_t)((((b * 64 + h) * 64 + w) * 2) * 2 + (d & 1)) * 192 + uc * 16;
        short8 dm0 = *(const short8*)(dp);
        short8 dm1 = *(const short8*)(dp + 384);
        const char* hp = hminp + (size_t)((((b * 32 + d) * 64 + w) * 4) * 2 + (h & 1)) * 192 + uc * 16;
        short8 hm0 = *(const short8*)(hp);
        short8 hm1 = *(const short8*)(hp + 384);
        short8 hm2 = *(const short8*)(hp + 768);
        short8 hm3 = *(const short8*)(hp + 1152);
        f4 a0 = *(const f4*)(cfA + cb), a1 = *(const f4*)(cfA + cb + 4);
        short8 xo;
#pragma unroll
        for (int e = 0; e < 8; ++e) {
            float m = fminf(
                fminf(bu2f((unsigned short)dm0[e]), bu2f((unsigned short)dm1[e])),
                fminf(fminf(fminf(bu2f((unsigned short)hm0[e]), bu2f((unsigned short)hm1[e])),
                            fminf(bu2f((unsigned short)hm2[e]), bu2f((unsigned short)hm3[e]))),
                      wlds[(w & 1) * 96 + cb + e]));
            float A = (e < 4) ? a0[e] : a1[e - 4];
            xo[e] = (short)f2bu(A * (bu2f((unsigned short)hv[j][e]) - m));
        }
        *(short8*)(xj + (size_t)(b * Sq + d * 4096 + h * 64 + w) * 192 + uc * 16) = xo;
    }
}

// ---------------------------------------------------------------------------
// ewx2: x2[v][c] = A3*y2 + B3 + xT (all bf16 streams, no LDS)
// ---------------------------------------------------------------------------
__global__ __launch_bounds__(256)
void ewx2_k(const char* __restrict__ y2, const float* __restrict__ cfA,
            const float* __restrict__ cfB, const char* __restrict__ xT,
            char* __restrict__ x2)
{
    size_t ch0 = ((size_t)blockIdx.x * 256 + threadIdx.x) * 4;
#pragma unroll
    for (int j = 0; j < 4; ++j) {
        size_t chunk = ch0 + j;
        int uc = (int)(chunk % 12), cb = uc * 8;
        short8 yv = *(const short8*)(y2 + chunk * 16);
        short8 xv = *(const short8*)(xT + chunk * 16);
        f4 a0 = *(const f4*)(cfA + cb), a1 = *(const f4*)(cfA + cb + 4);
        f4 d0 = *(const f4*)(cfB + cb), d1 = *(const f4*)(cfB + cb + 4);
        short8 o;
#pragma unroll
        for (int e = 0; e < 4; ++e) {
            float t0 = fmaf(a0[e], bu2f((unsigned short)yv[e]),     d0[e]) + bu2f((unsigned short)xv[e]);
            float t1 = fmaf(a1[e], bu2f((unsigned short)yv[e + 4]), d1[e]) + bu2f((unsigned short)xv[e + 4]);
            o[e]     = (short)f2bu(t0);
            o[e + 4] = (short)f2bu(t1);
        }
        *(short8*)(x2 + chunk * 16) = o;
    }
}

// ---------------------------------------------------------------------------
// tout: out f32 [b][c][s] = A5*y4 + B5 + x2   (transpose via LDS)
// ---------------------------------------------------------------------------
__global__ __launch_bounds__(256)
void tout_k(const char* __restrict__ y4, const float* __restrict__ cfA,
            const float* __restrict__ cfB, const char* __restrict__ x2,
            float* __restrict__ outp)
{
    __shared__ float ldsT[128 * 97];
    const int gm = blockIdx.x, b = gm >> 10, s0 = (gm & 1023) * 128;
    const int t = threadIdx.x;
#pragma unroll
    for (int i = 0; i < 6; ++i) {
        int idx = t + 256 * i;
        int r = idx / 12, uc = idx % 12, cb = uc * 8;
        size_t vv = (size_t)(b * Sq + s0 + r);
        short8 yv = *(const short8*)(y4 + vv * 192 + uc * 16);
        short8 xv = *(const short8*)(x2 + vv * 192 + uc * 16);
        f4 a0 = *(const f4*)(cfA + cb), a1 = *(const f4*)(cfA + cb + 4);
        f4 d0 = *(const f4*)(cfB + cb), d1 = *(const f4*)(cfB + cb + 4);
#pragma unroll
        for (int e = 0; e < 4; ++e) {
            ldsT[r * 97 + cb + e]     = fmaf(a0[e], bu2f((unsigned short)yv[e]),     d0[e]) + bu2f((unsigned short)xv[e]);
            ldsT[r * 97 + cb + e + 4] = fmaf(a1[e], bu2f((unsigned short)yv[e + 4]), d1[e]) + bu2f((unsigned short)xv[e + 4]);
        }
    }
    __syncthreads();
#pragma unroll
    for (int i = 0; i < 12; ++i) {
        int idx = t + 256 * i;
        int c = idx >> 5, s4 = idx & 31;
        f4 o;
#pragma unroll
        for (int j = 0; j < 4; ++j) o[j] = ldsT[(s4 * 4 + j) * 97 + c];
        *(f4*)(outp + ((size_t)(b * 96 + c) << 17) + s0 + s4 * 4) = o;
    }
}

// ===========================================================================
extern "C" void kernel_launch(void* const* d_in, const int* in_sizes, int n_in,
                              void* d_out, int out_size, void* d_ws, size_t ws_size,
                              hipStream_t stream)
{
    (void)in_sizes; (void)n_in; (void)out_size; (void)ws_size;

    const float* x      = (const float*)d_in[0];
    const float* w_fc1  = (const float*)d_in[1];
    const float* b_fc1  = (const float*)d_in[2];
    const float* g_bn1  = (const float*)d_in[3];
    const float* be_bn1 = (const float*)d_in[4];
    const float* w_g    = (const float*)d_in[5];
    const float* b_g    = (const float*)d_in[6];
    const float* g_in   = (const float*)d_in[7];
    const float* be_in  = (const float*)d_in[8];
    const float* w_fc2  = (const float*)d_in[9];
    const float* b_fc2  = (const float*)d_in[10];
    const float* g_bn2  = (const float*)d_in[11];
    const float* be_bn2 = (const float*)d_in[12];
    const float* w_f1   = (const float*)d_in[13];
    const float* b_f1   = (const float*)d_in[14];
    const float* g_bnf1 = (const float*)d_in[15];
    const float* be_bnf1= (const float*)d_in[16];
    const float* w_f2   = (const float*)d_in[17];
    const float* b_f2   = (const float*)d_in[18];
    const float* g_bnf2 = (const float*)d_in[19];
    const float* be_bnf2= (const float*)d_in[20];
    float* outp = (float*)d_out;

    char* W = (char*)d_ws;
    // layout (MiB): xT[0,48) y1[48,96) dminp[96,108) hminp[108,120)
    //               xj[120,168) yg[168,264) y2=y1 slot
    //               y3[0,192) y4[192,240) x2[240,288) misc[288,...)
    char* xT    = W;
    char* y1    = W + 50331648ull;
    char* dminp = W + 100663296ull;
    char* hminp = W + 113246208ull;
    char* xj    = W + 125829120ull;
    char* yg    = W + 176160768ull;
    char* y2    = W + 50331648ull;     // reuse y1 slot (y1 dead after conv g)
    char* y3    = W;                   // [0,192M) after xT/y1/mr fields die
    char* y4    = W + 201326592ull;
    char* x2    = W + 251658240ull;
    char* M     = W + 301989888ull;
    bf16*  Wb   = (bf16*)M;               // 307200 B
    float* cf   = (float*)(M + 307200);   // 5 slots x 2048 f32
    float* part = (float*)(M + 348160);   // 5 slots x 49152 f32

    hipMemsetAsync(part, 0, 5 * 196608, stream);

    const float invBN = 1.f / (float)NVq, invIN = 1.f / (float)Sq;
    dim3 blk(256);
    float* c1 = cf, *c2 = cf + 2048, *c3 = cf + 4096, *c4 = cf + 6144, *c5 = cf + 8192;

    wprep_k<<<600, blk, 0, stream>>>(w_fc1, w_g, w_fc2, w_f1, w_f2, Wb);
    tin_k<<<2048, blk, 0, stream>>>(x, xT);

    // fc1: 96 -> 96 (plain, gload_lds)
    conv_k<192, 128, 96, 96, 0, false><<<dim3(2048, 1), blk, 0, stream>>>(
        xT, nullptr, (const char*)Wb, b_fc1, nullptr, nullptr, (bf16*)y1, part);
    finalize_k<<<2, 64, 0, stream>>>(part, c1, g_bn1, be_bn1, 96, 96, 96, 0, invBN);

    // MRConv on raw y1 (A>0): partial mins, then xj = A*(y1 - min3)
    mr_dmin_k<<<dim3(8, 64, 2), dim3(192), 0, stream>>>(y1, dminp);
    mr_hmin_k<<<dim3(16, 32, 2), dim3(192), 0, stream>>>(y1, hminp);
    mr_p2_k<<<dim3(64, 32, 2), blk, 0, stream>>>(y1, c1, dminp, hminp, xj);

    // grapher conv: concat(y1-affine, xj) 192 -> 192, IN stats per (b,c)
    conv_k<192, 192, 192, 192, 4, true><<<dim3(2048, 1), blk, 0, stream>>>(
        y1, xj, (const char*)Wb + 24576, b_g, c1, c1 + 1024, (bf16*)yg, part + 49152);
    finalize_k<<<6, 64, 0, stream>>>(part + 49152, c2, g_in, be_in, 384, 192, 192, 1, invIN);

    // fc2: 192 -> 96, loader = lrelu(A2*yg+B2) per (b,c)
    conv_k<384, 192, 96, 96, 2, false><<<dim3(2048, 1), blk, 0, stream>>>(
        yg, nullptr, (const char*)Wb + 98304, b_fc2, c2, c2 + 1024, (bf16*)y2, part + 98304);
    finalize_k<<<2, 64, 0, stream>>>(part + 98304, c3, g_bn2, be_bn2, 96, 96, 96, 0, invBN);

    // x2 = A3*y2 + B3 + xT
    ewx2_k<<<3072, blk, 0, stream>>>(y2, c3, c3 + 1024, xT, x2);

    // f1: 96 -> 384, single dispatch (gy splits CO), full y3 [v][384]
    conv_k<192, 128, 384, 192, 0, false><<<dim3(2048, 2), blk, 0, stream>>>(
        x2, nullptr, (const char*)Wb + 135168, b_f1, nullptr, nullptr, (bf16*)y3, part + 147456);
    finalize_k<<<6, 64, 0, stream>>>(part + 147456, c4, g_bnf1, be_bnf1, 384, 384, 192, 0, invBN);

    // f2: 384 -> 96, loader = lrelu(A4*y3+B4) per c
    conv_k<768, 384, 96, 96, 1, false><<<dim3(2048, 1), blk, 0, stream>>>(
        y3, nullptr, (const char*)Wb + 233472, b_f2, c4, c4 + 1024, (bf16*)y4, part + 196608);
    finalize_k<<<2, 64, 0, stream>>>(part + 196608, c5, g_bnf2, be_bnf2, 96, 96, 96, 0, invBN);

    tout_k<<<2048, blk, 0, stream>>>(y4, c5, c5 + 1024, x2, outp);
}

// Round 6
// 451.953 us; speedup vs baseline: 1.2782x; 1.1315x over previous
//
#include <hip/hip_runtime.h>
#include <hip/hip_bf16.h>

// ============================================================================
// NexToU encoder block, MFMA bf16, [voxel][channel] layout. Round 6:
// FFN fusion — y3 (192MB x2 traffic) never hits HBM:
//   ffn_stats_k : x2 = A3*y2+B3+xT (write x2) + f1-GEMM stats-only -> BNf1
//   ffn_k       : fused f1+lrelu+BNf1+f2 via 64-ch chunks through LDS zbuf
// Grapher path unchanged from round 5 (proven 511us structure).
// ============================================================================

typedef __hip_bfloat16 bf16;
typedef __attribute__((ext_vector_type(8))) short short8;
typedef __attribute__((ext_vector_type(4))) float f4;
typedef __attribute__((ext_vector_type(4))) unsigned short us4;

#define DEV static __device__ __forceinline__

constexpr int Sq  = 131072;   // D*H*W
constexpr int NVq = 262144;   // B*S

DEV float bu2f(unsigned short u) { return __uint_as_float(((unsigned)u) << 16); }
DEV unsigned short f2bu(float f) {
    unsigned i = __float_as_uint(f);
    unsigned r = i + 0x7FFFu + ((i >> 16) & 1u);   // RNE (finite inputs only)
    return (unsigned short)(r >> 16);
}
DEV void glds16(const void* g, void* l) {
    __builtin_amdgcn_global_load_lds(
        (const __attribute__((address_space(1))) unsigned*)g,
        (__attribute__((address_space(3))) unsigned*)l, 16, 0, 0);
}

// ---------------------------------------------------------------------------
// MFMA conv (round-5 proven): Y[v][n] = sum_k A[v][k]*W[n][k] + bias, stats.
// ---------------------------------------------------------------------------
template<int CIRB, int KP, int CO, int BN, int AMODE, bool PERB>
__global__ __launch_bounds__(256)
void conv_k(const char* __restrict__ A0, const char* __restrict__ A1,
            const char* __restrict__ Wb, const float* __restrict__ bias,
            const float* __restrict__ cfA, const float* __restrict__ cfB,
            bf16* __restrict__ Y, float* __restrict__ part)
{
    constexpr int NSTEP = KP / 64;
    constexpr int NF = BN / 16;
    constexpr int BI = BN / 8;
    __shared__ __align__(16) char smem[16384 + BN * 128];
    char* As = smem;
    char* Bs = smem + 16384;

    const int tid = threadIdx.x;
    const int lane = tid & 63, wid = tid >> 6, l16 = lane & 15, lhi = lane >> 4;
    const int gm = blockIdx.x, gy = blockIdx.y;
    const int v0 = gm * 128;
    const int b = gm >> 10;
    const int n0g = gy * BN;

    f4 acc[2][NF];
#pragma unroll
    for (int nf = 0; nf < NF; ++nf) {
        float bb = bias[n0g + nf * 16 + l16];
        f4 t = {bb, bb, bb, bb};
        acc[0][nf] = t; acc[1][nf] = t;
    }

    for (int s = 0; s < NSTEP; ++s) {
        for (int i = wid; i < BI; i += 4) {
            int o = i * 8 + (lane >> 3);
            glds16(Wb + (size_t)(n0g + o) * (KP * 2) + s * 128 + (((lane & 7) ^ (o & 7)) << 4),
                   Bs + i * 1024);
        }
        if constexpr (AMODE == 0) {
            for (int i = wid; i < 16; i += 4) {
                int r = i * 8 + (lane >> 3);
                glds16(A0 + (size_t)(v0 + r) * CIRB + s * 128 + (((lane & 7) ^ (r & 7)) << 4),
                       As + i * 1024);
            }
        } else {
#pragma unroll
            for (int j = 0; j < 4; ++j) {
                int idx = tid + 256 * j;
                int v = idx >> 3, u = idx & 7;
                int k8 = s * 8 + u;
                short8 hh;
                if constexpr (AMODE == 2) {        // fc2: per-(b,c) affine+lrelu
                    short8 raw = *(const short8*)(A0 + (size_t)(v0 + v) * CIRB + k8 * 16);
                    int cb = b * KP + k8 * 8;
                    f4 a0 = *(const f4*)(cfA + cb), a1 = *(const f4*)(cfA + cb + 4);
                    f4 d0 = *(const f4*)(cfB + cb), d1 = *(const f4*)(cfB + cb + 4);
#pragma unroll
                    for (int e = 0; e < 4; ++e) {
                        float t0 = fmaf(a0[e], bu2f((unsigned short)raw[e]),     d0[e]);
                        float t1 = fmaf(a1[e], bu2f((unsigned short)raw[e + 4]), d1[e]);
                        t0 = fmaxf(t0, 0.2f * t0);
                        t1 = fmaxf(t1, 0.2f * t1);
                        hh[e] = (short)f2bu(t0); hh[e + 4] = (short)f2bu(t1);
                    }
                } else {                           // conv g: y1-affine | xj-plain
                    if (k8 < 12) {
                        short8 raw = *(const short8*)(A0 + (size_t)(v0 + v) * 192 + k8 * 16);
                        int cb = k8 * 8;
                        f4 a0 = *(const f4*)(cfA + cb), a1 = *(const f4*)(cfA + cb + 4);
                        f4 d0 = *(const f4*)(cfB + cb), d1 = *(const f4*)(cfB + cb + 4);
#pragma unroll
                        for (int e = 0; e < 4; ++e) {
                            hh[e]     = (short)f2bu(fmaf(a0[e], bu2f((unsigned short)raw[e]),     d0[e]));
                            hh[e + 4] = (short)f2bu(fmaf(a1[e], bu2f((unsigned short)raw[e + 4]), d1[e]));
                        }
                    } else {
                        hh = *(const short8*)(A1 + (size_t)(v0 + v) * 192 + (k8 - 12) * 16);
                    }
                }
                *(short8*)(As + v * 128 + ((u ^ (v & 7)) << 4)) = hh;
            }
        }
        __syncthreads();
#pragma unroll
        for (int ks = 0; ks < 2; ++ks) {
            int kg = ks * 4 + lhi;
            short8 av[2];
#pragma unroll
            for (int mf = 0; mf < 2; ++mf) {
                int v = wid * 32 + mf * 16 + l16;
                av[mf] = *(const short8*)(As + v * 128 + ((kg ^ (v & 7)) << 4));
            }
#pragma unroll
            for (int nf = 0; nf < NF; ++nf) {
                int o = nf * 16 + l16;
                short8 bv = *(const short8*)(Bs + o * 128 + ((kg ^ (o & 7)) << 4));
                acc[0][nf] = __builtin_amdgcn_mfma_f32_16x16x32_bf16(av[0], bv, acc[0][nf], 0, 0, 0);
                acc[1][nf] = __builtin_amdgcn_mfma_f32_16x16x32_bf16(av[1], bv, acc[1][nf], 0, 0, 0);
            }
        }
        __syncthreads();
    }

#pragma unroll
    for (int mf = 0; mf < 2; ++mf) {
        int vb = v0 + wid * 32 + mf * 16 + lhi * 4;
#pragma unroll
        for (int nf = 0; nf < NF; ++nf) {
            int n = n0g + nf * 16 + l16;
#pragma unroll
            for (int r = 0; r < 4; ++r) {
                bf16 o; *(unsigned short*)&o = f2bu(acc[mf][nf][r]);
                Y[(size_t)(vb + r) * CO + n] = o;
            }
        }
    }
    float* ps = (float*)smem;
#pragma unroll
    for (int nf = 0; nf < NF; ++nf) {
        float sm = 0.f, sq = 0.f;
#pragma unroll
        for (int mf = 0; mf < 2; ++mf)
#pragma unroll
            for (int r = 0; r < 4; ++r) {
                float v = acc[mf][nf][r];
                sm += v; sq += v * v;
            }
        sm += __shfl_xor(sm, 16); sq += __shfl_xor(sq, 16);
        sm += __shfl_xor(sm, 32); sq += __shfl_xor(sq, 32);
        if (lane < 16) {
            ps[(wid * 2 + 0) * BN + nf * 16 + lane] = sm;
            ps[(wid * 2 + 1) * BN + nf * 16 + lane] = sq;
        }
    }
    __syncthreads();
    if (tid < BN) {
        float sm = ps[0 * BN + tid] + ps[2 * BN + tid] + ps[4 * BN + tid] + ps[6 * BN + tid];
        float sq = ps[1 * BN + tid] + ps[3 * BN + tid] + ps[5 * BN + tid] + ps[7 * BN + tid];
        int slot = PERB ? (b * 32 + (gm & 31)) : (gm & 63);
        float* pb = part + (size_t)(gy * 64 + slot) * 2 * BN;
        atomicAdd(&pb[tid], sm);
        atomicAdd(&pb[BN + tid], sq);
    }
}

// ---------------------------------------------------------------------------
// ffn_stats_k: x2 = A3*y2+B3+xT (write global + keep in LDS), then f1 GEMM
// stats-only over 4 quarters of W1 (96 rows each). part layout [q][64][2][96].
// ---------------------------------------------------------------------------
__global__ __launch_bounds__(256)
void ffn_stats_k(const char* __restrict__ y2, const char* __restrict__ xT,
                 const float* __restrict__ cfA, const float* __restrict__ cfB,
                 const float* __restrict__ biasf1, const char* __restrict__ Wf1,
                 char* __restrict__ x2, float* __restrict__ part)
{
    __shared__ __align__(16) char smem[32768 + 24576];   // As[128][256], Bs[96][256]
    __shared__ float ps[8 * 96];
    char* As = smem;
    char* Bs = smem + 32768;

    const int tid = threadIdx.x;
    const int lane = tid & 63, wid = tid >> 6, l16 = lane & 15, lhi = lane >> 4;
    const int gm = blockIdx.x;
    const int v0 = gm * 128;

    // ---- compute x2 tile: 6 units per thread
#pragma unroll
    for (int j = 0; j < 6; ++j) {
        int slot = tid + 256 * j;
        int v = slot / 12, uc = slot % 12, cb = uc * 8;
        short8 yv = *(const short8*)(y2 + (size_t)(v0 + v) * 192 + uc * 16);
        short8 xv = *(const short8*)(xT + (size_t)(v0 + v) * 192 + uc * 16);
        f4 a0 = *(const f4*)(cfA + cb), a1 = *(const f4*)(cfA + cb + 4);
        f4 d0 = *(const f4*)(cfB + cb), d1 = *(const f4*)(cfB + cb + 4);
        short8 o;
#pragma unroll
        for (int e = 0; e < 4; ++e) {
            float t0 = fmaf(a0[e], bu2f((unsigned short)yv[e]),     d0[e]) + bu2f((unsigned short)xv[e]);
            float t1 = fmaf(a1[e], bu2f((unsigned short)yv[e + 4]), d1[e]) + bu2f((unsigned short)xv[e + 4]);
            o[e]     = (short)f2bu(t0);
            o[e + 4] = (short)f2bu(t1);
        }
        *(short8*)(x2 + (size_t)(v0 + v) * 192 + uc * 16) = o;
        *(short8*)(As + v * 256 + ((uc ^ (v & 7)) << 4)) = o;
    }

    for (int q = 0; q < 4; ++q) {
        // stage W1 quarter: 96 rows x 256B = 24 groups of 1024B
        for (int i = wid; i < 24; i += 4) {
            int o = i * 4 + (lane >> 4), u = lane & 15;
            glds16(Wf1 + (size_t)(q * 96 + o) * 192 + ((u ^ (o & 7)) << 4),
                   Bs + i * 1024);
        }
        __syncthreads();
        f4 acc[2][6];
#pragma unroll
        for (int nf = 0; nf < 6; ++nf) {
            float bb = biasf1[q * 96 + nf * 16 + l16];
            f4 t = {bb, bb, bb, bb};
            acc[0][nf] = t; acc[1][nf] = t;
        }
#pragma unroll
        for (int ks = 0; ks < 3; ++ks) {
            int kg = ks * 4 + lhi;
            short8 av[2];
#pragma unroll
            for (int mf = 0; mf < 2; ++mf) {
                int v = wid * 32 + mf * 16 + l16;
                av[mf] = *(const short8*)(As + v * 256 + ((kg ^ (v & 7)) << 4));
            }
#pragma unroll
            for (int nf = 0; nf < 6; ++nf) {
                int o = nf * 16 + l16;
                short8 bv = *(const short8*)(Bs + o * 256 + ((kg ^ (o & 7)) << 4));
                acc[0][nf] = __builtin_amdgcn_mfma_f32_16x16x32_bf16(av[0], bv, acc[0][nf], 0, 0, 0);
                acc[1][nf] = __builtin_amdgcn_mfma_f32_16x16x32_bf16(av[1], bv, acc[1][nf], 0, 0, 0);
            }
        }
        // stats
#pragma unroll
        for (int nf = 0; nf < 6; ++nf) {
            float sm = 0.f, sq = 0.f;
#pragma unroll
            for (int mf = 0; mf < 2; ++mf)
#pragma unroll
                for (int r = 0; r < 4; ++r) {
                    float v = acc[mf][nf][r];
                    sm += v; sq += v * v;
                }
            sm += __shfl_xor(sm, 16); sq += __shfl_xor(sq, 16);
            sm += __shfl_xor(sm, 32); sq += __shfl_xor(sq, 32);
            if (lane < 16) {
                ps[(wid * 2 + 0) * 96 + nf * 16 + lane] = sm;
                ps[(wid * 2 + 1) * 96 + nf * 16 + lane] = sq;
            }
        }
        __syncthreads();
        if (tid < 96) {
            float sm = ps[0 * 96 + tid] + ps[2 * 96 + tid] + ps[4 * 96 + tid] + ps[6 * 96 + tid];
            float sq = ps[1 * 96 + tid] + ps[3 * 96 + tid] + ps[5 * 96 + tid] + ps[7 * 96 + tid];
            float* pb = part + (size_t)(q * 64 + (gm & 63)) * 192;
            atomicAdd(&pb[tid], sm);
            atomicAdd(&pb[96 + tid], sq);
        }
    }
}

// ---------------------------------------------------------------------------
// ffn_k: fused f1+lrelu+BNf1+f2. Per 128-voxel block, 6 chunks of 64 y3-ch:
//   GEMM1 (swapped, D rows=ch) -> lrelu(A4*z+B4') -> zbuf (LDS, XOR) ->
//   GEMM2 accumulates y4. BNf2 stats fused. y3 never in HBM.
// ---------------------------------------------------------------------------
__global__ __launch_bounds__(256)
void ffn_k(const char* __restrict__ x2, const float* __restrict__ cfA4,
           const float* __restrict__ cfB4, const float* __restrict__ biasf2,
           const char* __restrict__ Wf1, const char* __restrict__ Wf2,
           bf16* __restrict__ y4, float* __restrict__ part)
{
    __shared__ __align__(16) char smem[32768 + 16384 + 12288 + 16384];
    char* As  = smem;                    // x2 tile [128][256B]
    char* W1c = smem + 32768;            // [64][256B]
    char* W2c = smem + 49152;            // [96][128B]
    char* zb  = smem + 61440;            // [128][128B]
    float* ps = (float*)zb;              // aliased after last GEMM2

    const int tid = threadIdx.x;
    const int lane = tid & 63, wid = tid >> 6, l16 = lane & 15, lhi = lane >> 4;
    const int gm = blockIdx.x;
    const int v0 = gm * 128;

    // stage x2 tile: 128 rows x 256B = 32 groups
    for (int i = wid; i < 32; i += 4) {
        int v = i * 4 + (lane >> 4), u = lane & 15;
        glds16(x2 + (size_t)(v0 + v) * 192 + ((u ^ (v & 7)) << 4), As + i * 1024);
    }

    f4 accY[2][6];
#pragma unroll
    for (int nf = 0; nf < 6; ++nf) {
        float bb = biasf2[nf * 16 + l16];
        f4 t = {bb, bb, bb, bb};
        accY[0][nf] = t; accY[1][nf] = t;
    }

    for (int nc = 0; nc < 6; ++nc) {
        // stage W1 chunk: 64 rows x 256B = 16 groups
        for (int i = wid; i < 16; i += 4) {
            int o = i * 4 + (lane >> 4), u = lane & 15;
            glds16(Wf1 + (size_t)(nc * 64 + o) * 192 + ((u ^ (o & 7)) << 4),
                   W1c + i * 1024);
        }
        // stage W2 K-slice: 96 rows x 128B = 12 groups
        for (int i = wid; i < 12; i += 4) {
            int o = i * 8 + (lane >> 3), u = lane & 7;
            glds16(Wf2 + (size_t)o * 768 + nc * 128 + ((u ^ (o & 7)) << 4),
                   W2c + i * 1024);
        }
        __syncthreads();
        // GEMM1 swapped: z[mt][nt], D row = chunk-channel, col = voxel
        f4 z[4][2];
#pragma unroll
        for (int mt = 0; mt < 4; ++mt)
#pragma unroll
            for (int nt = 0; nt < 2; ++nt) z[mt][nt] = {0.f, 0.f, 0.f, 0.f};
#pragma unroll
        for (int ks = 0; ks < 3; ++ks) {
            int kg = ks * 4 + lhi;
            short8 xv[2];
#pragma unroll
            for (int nt = 0; nt < 2; ++nt) {
                int v = wid * 32 + nt * 16 + l16;
                xv[nt] = *(const short8*)(As + v * 256 + ((kg ^ (v & 7)) << 4));
            }
#pragma unroll
            for (int mt = 0; mt < 4; ++mt) {
                int o = mt * 16 + l16;
                short8 wv = *(const short8*)(W1c + o * 256 + ((kg ^ (o & 7)) << 4));
                z[mt][0] = __builtin_amdgcn_mfma_f32_16x16x32_bf16(wv, xv[0], z[mt][0], 0, 0, 0);
                z[mt][1] = __builtin_amdgcn_mfma_f32_16x16x32_bf16(wv, xv[1], z[mt][1], 0, 0, 0);
            }
        }
        // lrelu(A4*z + B4') -> zbuf [v][64ch], us4 writes, XOR-swizzled
#pragma unroll
        for (int mt = 0; mt < 4; ++mt) {
            int ch = nc * 64 + mt * 16 + lhi * 4;
            f4 a = *(const f4*)(cfA4 + ch);
            f4 bb = *(const f4*)(cfB4 + ch);
#pragma unroll
            for (int nt = 0; nt < 2; ++nt) {
                int v = wid * 32 + nt * 16 + l16;
                us4 p;
#pragma unroll
                for (int r = 0; r < 4; ++r) {
                    float t = fmaf(a[r], z[mt][nt][r], bb[r]);
                    t = fmaxf(t, 0.2f * t);
                    p[r] = f2bu(t);
                }
                *(us4*)(zb + v * 128 + (((mt * 2 + (lhi >> 1)) ^ (v & 7)) << 4) + ((lhi & 1) << 3)) = p;
            }
        }
        __syncthreads();
        // GEMM2: accY += z x W2c  (K = 64)
#pragma unroll
        for (int ks = 0; ks < 2; ++ks) {
            int kg = ks * 4 + lhi;
            short8 av[2];
#pragma unroll
            for (int mf = 0; mf < 2; ++mf) {
                int v = wid * 32 + mf * 16 + l16;
                av[mf] = *(const short8*)(zb + v * 128 + ((kg ^ (v & 7)) << 4));
            }
#pragma unroll
            for (int nf = 0; nf < 6; ++nf) {
                int o = nf * 16 + l16;
                short8 bv = *(const short8*)(W2c + o * 128 + ((kg ^ (o & 7)) << 4));
                accY[0][nf] = __builtin_amdgcn_mfma_f32_16x16x32_bf16(av[0], bv, accY[0][nf], 0, 0, 0);
                accY[1][nf] = __builtin_amdgcn_mfma_f32_16x16x32_bf16(av[1], bv, accY[1][nf], 0, 0, 0);
            }
        }
        __syncthreads();
    }

    // store y4 + BNf2 stats
#pragma unroll
    for (int mf = 0; mf < 2; ++mf) {
        int vb = v0 + wid * 32 + mf * 16 + lhi * 4;
#pragma unroll
        for (int nf = 0; nf < 6; ++nf) {
            int n = nf * 16 + l16;
#pragma unroll
            for (int r = 0; r < 4; ++r) {
                bf16 o; *(unsigned short*)&o = f2bu(accY[mf][nf][r]);
                y4[(size_t)(vb + r) * 96 + n] = o;
            }
        }
    }
#pragma unroll
    for (int nf = 0; nf < 6; ++nf) {
        float sm = 0.f, sq = 0.f;
#pragma unroll
        for (int mf = 0; mf < 2; ++mf)
#pragma unroll
            for (int r = 0; r < 4; ++r) {
                float v = accY[mf][nf][r];
                sm += v; sq += v * v;
            }
        sm += __shfl_xor(sm, 16); sq += __shfl_xor(sq, 16);
        sm += __shfl_xor(sm, 32); sq += __shfl_xor(sq, 32);
        if (lane < 16) {
            ps[(wid * 2 + 0) * 96 + nf * 16 + lane] = sm;
            ps[(wid * 2 + 1) * 96 + nf * 16 + lane] = sq;
        }
    }
    __syncthreads();
    if (tid < 96) {
        float sm = ps[0 * 96 + tid] + ps[2 * 96 + tid] + ps[4 * 96 + tid] + ps[6 * 96 + tid];
        float sq = ps[1 * 96 + tid] + ps[3 * 96 + tid] + ps[5 * 96 + tid] + ps[7 * 96 + tid];
        float* pb = part + (size_t)(gm & 63) * 192;
        atomicAdd(&pb[tid], sm);
        atomicAdd(&pb[96 + tid], sq);
    }
}

// ---------------------------------------------------------------------------
// partial sums -> affine coefs  A = g*rsqrt(var+eps), B = be - m*A (+ A*bias)
// ---------------------------------------------------------------------------
__global__ void finalize_k(const float* __restrict__ part, float* __restrict__ cf,
                           const float* __restrict__ g, const float* __restrict__ be,
                           const float* __restrict__ bias,
                           int nStats, int CO, int BN, int perB, float invN)
{
    int s = blockIdx.x * 64 + threadIdx.x;
    if (s >= nStats) return;
    int ch = perB ? (s % CO) : s;
    int bb = perB ? (s / CO) : 0;
    int gy = ch / BN, c = ch - gy * BN;
    int j0 = perB ? bb * 32 : 0, cnt = perB ? 32 : 64;
    float sm = 0.f, sq = 0.f;
    for (int j = 0; j < cnt; ++j) {
        const float* pb = part + (size_t)(gy * 64 + j0 + j) * 2 * BN;
        sm += pb[c]; sq += pb[BN + c];
    }
    float m = sm * invN;
    float var = fmaf(-m, m, sq * invN);
    float A = g[ch] * rsqrtf(var + 1e-5f);
    cf[s] = A;
    float B = fmaf(-m, A, be[ch]);
    if (bias) B = fmaf(A, bias[ch], B);
    cf[1024 + s] = B;
}

// ---------------------------------------------------------------------------
// weight prep: f32 [CO][CI] -> bf16 [CO][KP] (KP in elements)
//   fc1 [96][128] @0 | g [192][192] @12288 | fc2 [96][192] @49152
//   f1 [384][96] @67584 (packed) | f2 [96][384] @104448
// ---------------------------------------------------------------------------
__global__ void wprep_k(const float* __restrict__ w0, const float* __restrict__ w1,
                        const float* __restrict__ w2, const float* __restrict__ w3,
                        const float* __restrict__ w4, bf16* __restrict__ Wb)
{
    int i = blockIdx.x * 256 + threadIdx.x;     // < 141312
    if (i >= 141312) return;
    const float* src; int r, KP, CI, off;
    if (i < 12288)       { src = w0; r = i;          KP = 128; CI = 96;  off = 0; }
    else if (i < 49152)  { src = w1; r = i - 12288;  KP = 192; CI = 192; off = 12288; }
    else if (i < 67584)  { src = w2; r = i - 49152;  KP = 192; CI = 192; off = 49152; }
    else if (i < 104448) { src = w3; r = i - 67584;  KP = 96;  CI = 96;  off = 67584; }
    else                 { src = w4; r = i - 104448; KP = 384; CI = 384; off = 104448; }
    int o = r / KP, k = r - o * KP;
    float v = (k < CI) ? src[o * CI + k] : 0.f;
    bf16 h; *(unsigned short*)&h = f2bu(v);
    Wb[off + r] = h;
}

// ---------------------------------------------------------------------------
// tin: x f32 [b][c][s] -> xT bf16 [v][96] via LDS transpose
// ---------------------------------------------------------------------------
__global__ __launch_bounds__(256)
void tin_k(const float* __restrict__ x, char* __restrict__ xT)
{
    __shared__ float ldsT[128 * 97];
    const int gm = blockIdx.x, b = gm >> 10, s0 = (gm & 1023) * 128;
    const int t = threadIdx.x;
#pragma unroll
    for (int i = 0; i < 12; ++i) {
        int idx = t + 256 * i;
        int c = idx >> 5, s4 = idx & 31;
        f4 r = *(const f4*)(x + ((size_t)(b * 96 + c) << 17) + s0 + s4 * 4);
#pragma unroll
        for (int j = 0; j < 4; ++j) ldsT[(s4 * 4 + j) * 97 + c] = r[j];
    }
    __syncthreads();
#pragma unroll
    for (int i = 0; i < 6; ++i) {
        int idx = t + 256 * i;
        int r = idx / 12, uc = idx % 12, cb = uc * 8;
        short8 o;
#pragma unroll
        for (int e = 0; e < 8; ++e) o[e] = (short)f2bu(ldsT[r * 97 + cb + e]);
        *(short8*)(xT + (size_t)(b * Sq + s0 + r) * 192 + uc * 16) = o;
    }
}

// ---------------------------------------------------------------------------
// MR pass 1a/1b/2: unchanged from round 5
// ---------------------------------------------------------------------------
__global__ __launch_bounds__(192)
void mr_dmin_k(const char* __restrict__ y1, char* __restrict__ dminp)
{
    const int wq = blockIdx.x >> 1, dh = blockIdx.x & 1;
    const int h = blockIdx.y, b = blockIdx.z;
    const int t = threadIdx.x;
    const int w = wq * 16 + t / 12, uc = t % 12;
    const char* base = y1 + (size_t)(b * Sq + dh * 16 * 4096 + h * 64 + w) * 192 + uc * 16;
    float mn[2][8];
#pragma unroll
    for (int p = 0; p < 2; ++p)
#pragma unroll
        for (int e = 0; e < 8; ++e) mn[p][e] = 1e30f;
#pragma unroll 4
    for (int i = 0; i < 16; ++i) {
        short8 raw = *(const short8*)(base + (size_t)i * (4096 * 192));
        int p = i & 1;
#pragma unroll
        for (int e = 0; e < 8; ++e)
            mn[p][e] = fminf(mn[p][e], bu2f((unsigned short)raw[e]));
    }
#pragma unroll
    for (int p = 0; p < 2; ++p) {
        short8 o;
#pragma unroll
        for (int e = 0; e < 8; ++e) o[e] = (short)f2bu(mn[p][e]);
        *(short8*)(dminp + (size_t)((((b * 64 + h) * 64 + w) * 2 + dh) * 2 + p) * 192 + uc * 16) = o;
    }
}

__global__ __launch_bounds__(192)
void mr_hmin_k(const char* __restrict__ y1, char* __restrict__ hminp)
{
    const int wq = blockIdx.x >> 2, hq = blockIdx.x & 3;
    const int d = blockIdx.y, b = blockIdx.z;
    const int t = threadIdx.x;
    const int w = wq * 16 + t / 12, uc = t % 12;
    const char* base = y1 + (size_t)(b * Sq + d * 4096 + hq * 16 * 64 + w) * 192 + uc * 16;
    float mn[2][8];
#pragma unroll
    for (int p = 0; p < 2; ++p)
#pragma unroll
        for (int e = 0; e < 8; ++e) mn[p][e] = 1e30f;
#pragma unroll 4
    for (int i = 0; i < 16; ++i) {
        short8 raw = *(const short8*)(base + (size_t)i * (64 * 192));
        int p = i & 1;
#pragma unroll
        for (int e = 0; e < 8; ++e)
            mn[p][e] = fminf(mn[p][e], bu2f((unsigned short)raw[e]));
    }
#pragma unroll
    for (int p = 0; p < 2; ++p) {
        short8 o;
#pragma unroll
        for (int e = 0; e < 8; ++e) o[e] = (short)f2bu(mn[p][e]);
        *(short8*)(hminp + (size_t)((((b * 32 + d) * 64 + w) * 4 + hq) * 2 + p) * 192 + uc * 16) = o;
    }
}

__global__ __launch_bounds__(256)
void mr_p2_k(const char* __restrict__ y1, const float* __restrict__ cfA,
             const char* __restrict__ dminp, const char* __restrict__ hminp,
             char* __restrict__ xj)
{
    __shared__ __align__(16) char rowb[64 * 96 * 2];
    __shared__ float wlds[2 * 96];
    const int h = blockIdx.x, d = blockIdx.y, b = blockIdx.z;
    const int t = threadIdx.x;

    short8 hv[3];
#pragma unroll
    for (int j = 0; j < 3; ++j) {
        int slot = t + 256 * j;
        int w = slot / 12, uc = slot % 12;
        short8 raw = *(const short8*)(y1 + (size_t)(b * Sq + d * 4096 + h * 64 + w) * 192 + uc * 16);
        hv[j] = raw;
        *(short8*)(rowb + slot * 16) = raw;
    }
    __syncthreads();
    if (t < 192) {
        int p = t / 96, c = t % 96;
        float m = 1e30f;
        for (int w2 = p; w2 < 64; w2 += 2)
            m = fminf(m, bu2f(*(const unsigned short*)(rowb + (w2 * 96 + c) * 2)));
        wlds[t] = m;
    }
    __syncthreads();
#pragma unroll
    for (int j = 0; j < 3; ++j) {
        int slot = t + 256 * j;
        int w = slot / 12, uc = slot % 12, cb = uc * 8;
        const char* dp = dminp + (size_t)((((b * 64 + h) * 64 + w) * 2) * 2 + (d & 1)) * 192 + uc * 16;
        short8 dm0 = *(const short8*)(dp);
        short8 dm1 = *(const short8*)(dp + 384);
        const char* hp = hminp + (size_t)((((b * 32 + d) * 64 + w) * 4) * 2 + (h & 1)) * 192 + uc * 16;
        short8 hm0 = *(const short8*)(hp);
        short8 hm1 = *(const short8*)(hp + 384);
        short8 hm2 = *(const short8*)(hp + 768);
        short8 hm3 = *(const short8*)(hp + 1152);
        f4 a0 = *(const f4*)(cfA + cb), a1 = *(const f4*)(cfA + cb + 4);
        short8 xo;
#pragma unroll
        for (int e = 0; e < 8; ++e) {
            float m = fminf(
                fminf(bu2f((unsigned short)dm0[e]), bu2f((unsigned short)dm1[e])),
                fminf(fminf(fminf(bu2f((unsigned short)hm0[e]), bu2f((unsigned short)hm1[e])),
                            fminf(bu2f((unsigned short)hm2[e]), bu2f((unsigned short)hm3[e]))),
                      wlds[(w & 1) * 96 + cb + e]));
            float A = (e < 4) ? a0[e] : a1[e - 4];
            xo[e] = (short)f2bu(A * (bu2f((unsigned short)hv[j][e]) - m));
        }
        *(short8*)(xj + (size_t)(b * Sq + d * 4096 + h * 64 + w) * 192 + uc * 16) = xo;
    }
}

// ---------------------------------------------------------------------------
// tout: out f32 [b][c][s] = A5*y4 + B5 + x2   (transpose via LDS)
// ---------------------------------------------------------------------------
__global__ __launch_bounds__(256)
void tout_k(const char* __restrict__ y4, const float* __restrict__ cfA,
            const float* __restrict__ cfB, const char* __restrict__ x2,
            float* __restrict__ outp)
{
    __shared__ float ldsT[128 * 97];
    const int gm = blockIdx.x, b = gm >> 10, s0 = (gm & 1023) * 128;
    const int t = threadIdx.x;
#pragma unroll
    for (int i = 0; i < 6; ++i) {
        int idx = t + 256 * i;
        int r = idx / 12, uc = idx % 12, cb = uc * 8;
        size_t vv = (size_t)(b * Sq + s0 + r);
        short8 yv = *(const short8*)(y4 + vv * 192 + uc * 16);
        short8 xv = *(const short8*)(x2 + vv * 192 + uc * 16);
        f4 a0 = *(const f4*)(cfA + cb), a1 = *(const f4*)(cfA + cb + 4);
        f4 d0 = *(const f4*)(cfB + cb), d1 = *(const f4*)(cfB + cb + 4);
#pragma unroll
        for (int e = 0; e < 4; ++e) {
            ldsT[r * 97 + cb + e]     = fmaf(a0[e], bu2f((unsigned short)yv[e]),     d0[e]) + bu2f((unsigned short)xv[e]);
            ldsT[r * 97 + cb + e + 4] = fmaf(a1[e], bu2f((unsigned short)yv[e + 4]), d1[e]) + bu2f((unsigned short)xv[e + 4]);
        }
    }
    __syncthreads();
#pragma unroll
    for (int i = 0; i < 12; ++i) {
        int idx = t + 256 * i;
        int c = idx >> 5, s4 = idx & 31;
        f4 o;
#pragma unroll
        for (int j = 0; j < 4; ++j) o[j] = ldsT[(s4 * 4 + j) * 97 + c];
        *(f4*)(outp + ((size_t)(b * 96 + c) << 17) + s0 + s4 * 4) = o;
    }
}

// ===========================================================================
extern "C" void kernel_launch(void* const* d_in, const int* in_sizes, int n_in,
                              void* d_out, int out_size, void* d_ws, size_t ws_size,
                              hipStream_t stream)
{
    (void)in_sizes; (void)n_in; (void)out_size; (void)ws_size;

    const float* x      = (const float*)d_in[0];
    const float* w_fc1  = (const float*)d_in[1];
    const float* b_fc1  = (const float*)d_in[2];
    const float* g_bn1  = (const float*)d_in[3];
    const float* be_bn1 = (const float*)d_in[4];
    const float* w_g    = (const float*)d_in[5];
    const float* b_g    = (const float*)d_in[6];
    const float* g_in   = (const float*)d_in[7];
    const float* be_in  = (const float*)d_in[8];
    const float* w_fc2  = (const float*)d_in[9];
    const float* b_fc2  = (const float*)d_in[10];
    const float* g_bn2  = (const float*)d_in[11];
    const float* be_bn2 = (const float*)d_in[12];
    const float* w_f1   = (const float*)d_in[13];
    const float* b_f1   = (const float*)d_in[14];
    const float* g_bnf1 = (const float*)d_in[15];
    const float* be_bnf1= (const float*)d_in[16];
    const float* w_f2   = (const float*)d_in[17];
    const float* b_f2   = (const float*)d_in[18];
    const float* g_bnf2 = (const float*)d_in[19];
    const float* be_bnf2= (const float*)d_in[20];
    float* outp = (float*)d_out;

    char* W = (char*)d_ws;
    // layout (MiB): xT[0,48) y1[48,96) dminp[96,108) hminp[108,120)
    //   xj[120,168) yg[168,264) y2=y1 slot | y4[192,240) x2[240,288)
    //   (yg dead before y4/x2 written) misc[288,...)
    char* xT    = W;
    char* y1    = W + 50331648ull;
    char* dminp = W + 100663296ull;
    char* hminp = W + 113246208ull;
    char* xj    = W + 125829120ull;
    char* yg    = W + 176160768ull;
    char* y2    = W + 50331648ull;
    char* y4    = W + 201326592ull;
    char* x2    = W + 251658240ull;
    char* M     = W + 301989888ull;
    bf16*  Wb   = (bf16*)M;               // 282624 B
    float* cf   = (float*)(M + 307200);   // 5 slots x 2048 f32
    float* part = (float*)(M + 348160);   // 5 slots x 49152 f32

    hipMemsetAsync(part, 0, 5 * 196608, stream);

    const float invBN = 1.f / (float)NVq, invIN = 1.f / (float)Sq;
    dim3 blk(256);
    float* c1 = cf, *c2 = cf + 2048, *c3 = cf + 4096, *c4 = cf + 6144, *c5 = cf + 8192;
    const char* Wfc1 = (const char*)Wb;
    const char* Wg   = (const char*)Wb + 24576;
    const char* Wfc2 = (const char*)Wb + 98304;
    const char* Wf1  = (const char*)Wb + 135168;
    const char* Wf2  = (const char*)Wb + 208896;

    wprep_k<<<552, blk, 0, stream>>>(w_fc1, w_g, w_fc2, w_f1, w_f2, Wb);
    tin_k<<<2048, blk, 0, stream>>>(x, xT);

    // fc1: 96 -> 96 (plain, gload_lds)
    conv_k<192, 128, 96, 96, 0, false><<<dim3(2048, 1), blk, 0, stream>>>(
        xT, nullptr, Wfc1, b_fc1, nullptr, nullptr, (bf16*)y1, part);
    finalize_k<<<2, 64, 0, stream>>>(part, c1, g_bn1, be_bn1, nullptr, 96, 96, 96, 0, invBN);

    // MRConv on raw y1 (A>0): partial mins, then xj = A*(y1 - min3)
    mr_dmin_k<<<dim3(8, 64, 2), dim3(192), 0, stream>>>(y1, dminp);
    mr_hmin_k<<<dim3(16, 32, 2), dim3(192), 0, stream>>>(y1, hminp);
    mr_p2_k<<<dim3(64, 32, 2), blk, 0, stream>>>(y1, c1, dminp, hminp, xj);

    // grapher conv: concat(y1-affine, xj) 192 -> 192, IN stats per (b,c)
    conv_k<192, 192, 192, 192, 4, true><<<dim3(2048, 1), blk, 0, stream>>>(
        y1, xj, Wg, b_g, c1, c1 + 1024, (bf16*)yg, part + 49152);
    finalize_k<<<6, 64, 0, stream>>>(part + 49152, c2, g_in, be_in, nullptr, 384, 192, 192, 1, invIN);

    // fc2: 192 -> 96, loader = lrelu(A2*yg+B2) per (b,c)
    conv_k<384, 192, 96, 96, 2, false><<<dim3(2048, 1), blk, 0, stream>>>(
        yg, nullptr, Wfc2, b_fc2, c2, c2 + 1024, (bf16*)y2, part + 98304);
    finalize_k<<<2, 64, 0, stream>>>(part + 98304, c3, g_bn2, be_bn2, nullptr, 96, 96, 96, 0, invBN);

    // FFN phase 1: x2 = A3*y2+B3+xT (write) + f1 stats-only -> BNf1 partials
    ffn_stats_k<<<2048, blk, 0, stream>>>(y2, xT, c3, c3 + 1024, b_f1, Wf1, x2, part + 147456);
    finalize_k<<<6, 64, 0, stream>>>(part + 147456, c4, g_bnf1, be_bnf1, b_f1, 384, 384, 96, 0, invBN);

    // FFN phase 2: fused f1+lrelu+f2 -> y4 + BNf2 partials
    ffn_k<<<2048, blk, 0, stream>>>(x2, c4, c4 + 1024, b_f2, Wf1, Wf2, (bf16*)y4, part + 196608);
    finalize_k<<<2, 64, 0, stream>>>(part + 196608, c5, g_bnf2, be_bnf2, nullptr, 96, 96, 96, 0, invBN);

    tout_k<<<2048, blk, 0, stream>>>(y4, c5, c5 + 1024, x2, outp);
}